// Round 1
// baseline (1641.701 us; speedup 1.0000x reference)
//
#include <hip/hip_runtime.h>
#include <math.h>

// ---------------------------------------------------------------------------
// SwinV2 stage: B=32, H=W=56, C=128, NH=4, hd=32, WS=7, N=49, DEPTH=2, shift=3
// fp32 end-to-end (round 1: correctness + sane memory behavior).
// ---------------------------------------------------------------------------

namespace {
constexpr int kTok = 32 * 56 * 56;   // 100352 tokens
}

__device__ __forceinline__ float gelu_f(float x) {
    return 0.5f * x * (1.0f + erff(x * 0.70710678118654752f));
}

// region label for the shifted-window mask (coordinates in rolled frame)
__device__ __forceinline__ int region3(int r) {
    return (r < 49) ? 0 : ((r < 53) ? 1 : 2);
}

// --------------------------- CPB MLP (tiny) --------------------------------
// out169[t][h] = (relu(table[t] @ w1 + b1) @ w2)[h],  t in [0,169)
__global__ __launch_bounds__(256) void k_cpb(
    const float* __restrict__ w1, const float* __restrict__ b1,
    const float* __restrict__ w2, float* __restrict__ out169) {
    int t = blockIdx.x;  // 0..168
    int ia = t / 13, ib = t % 13;
    float r0 = (float)(ia - 6) * (8.0f / 6.0f);
    float s0 = (r0 > 0.f) ? 1.f : (r0 < 0.f ? -1.f : 0.f);
    float t0 = s0 * log2f(fabsf(r0) + 1.0f) * (1.0f / 3.0f);
    float r1 = (float)(ib - 6) * (8.0f / 6.0f);
    float s1 = (r1 > 0.f) ? 1.f : (r1 < 0.f ? -1.f : 0.f);
    float t1 = s1 * log2f(fabsf(r1) + 1.0f) * (1.0f / 3.0f);

    int tid = threadIdx.x;
    float p0 = 0, p1 = 0, p2 = 0, p3 = 0;
    for (int c = tid; c < 512; c += 256) {
        float hv = fmaxf(t0 * w1[c] + t1 * w1[512 + c] + b1[c], 0.0f);
        p0 += hv * w2[c * 4 + 0];
        p1 += hv * w2[c * 4 + 1];
        p2 += hv * w2[c * 4 + 2];
        p3 += hv * w2[c * 4 + 3];
    }
    __shared__ float red[256][4];
    red[tid][0] = p0; red[tid][1] = p1; red[tid][2] = p2; red[tid][3] = p3;
    __syncthreads();
    for (int s = 128; s > 0; s >>= 1) {
        if (tid < s) {
            red[tid][0] += red[tid + s][0];
            red[tid][1] += red[tid + s][1];
            red[tid][2] += red[tid + s][2];
            red[tid][3] += red[tid + s][3];
        }
        __syncthreads();
    }
    if (tid < 4) out169[t * 4 + tid] = red[0][tid];
}

// rpb[h][i][j] = 16*sigmoid(out169[relidx(i,j)][h])
__global__ void k_rpb(const float* __restrict__ out169, float* __restrict__ rpb) {
    int e = blockIdx.x * 256 + threadIdx.x;
    if (e >= 4 * 49 * 49) return;
    int h = e / 2401, r = e % 2401;
    int i = r / 49, j = r % 49;
    int dp = i / 7 - j / 7 + 6;
    int dq = i % 7 - j % 7 + 6;
    float v = out169[(dp * 13 + dq) * 4 + h];
    rpb[e] = 16.0f / (1.0f + expf(-v));
}

// --------------------------- QKV GEMM --------------------------------------
// out[m][0:384] = x_rolled[m] @ qkv_w + concat(q_bias, 0, v_bias)
// grid (1568, 3), block 256. 64 tokens x 128-col chunk per block.
__global__ __launch_bounds__(256) void k_qkv(
    const float* __restrict__ xin, const float* __restrict__ w,
    const float* __restrict__ qb, const float* __restrict__ vb,
    float* __restrict__ out, int shift) {
    __shared__ float4 xs4[64][32];
    const float* xs = (const float*)xs4;
    int tid = threadIdx.x;
    int mb = blockIdx.x * 64;
    int ncb = blockIdx.y * 128;
#pragma unroll
    for (int it = 0; it < 8; ++it) {
        int e = it * 256 + tid;
        int t = e >> 5, k4 = e & 31;
        int m = mb + t;
        int b = m / 3136, r = m % 3136;
        int hh = r / 56, ww = r % 56;
        hh += shift; if (hh >= 56) hh -= 56;
        ww += shift; if (ww >= 56) ww -= 56;
        xs4[t][k4] = ((const float4*)(xin + (size_t)(b * 3136 + hh * 56 + ww) * 128))[k4];
    }
    __syncthreads();
    int tx = tid & 31, ty = tid >> 5;
    float acc[8][4] = {};
    const float* wp = w + ncb + tx * 4;
    const float* xrow = xs + ty * 8 * 128;
#pragma unroll 4
    for (int k = 0; k < 128; ++k) {
        float4 wv = *(const float4*)(wp + (size_t)k * 384);
#pragma unroll
        for (int t = 0; t < 8; ++t) {
            float xa = xrow[t * 128 + k];
            acc[t][0] = fmaf(xa, wv.x, acc[t][0]);
            acc[t][1] = fmaf(xa, wv.y, acc[t][1]);
            acc[t][2] = fmaf(xa, wv.z, acc[t][2]);
            acc[t][3] = fmaf(xa, wv.w, acc[t][3]);
        }
    }
    int col = ncb + tx * 4;
    float bv[4];
#pragma unroll
    for (int cc = 0; cc < 4; ++cc) {
        int cg = col + cc;
        bv[cc] = (cg < 128) ? qb[cg] : ((cg < 256) ? 0.0f : vb[cg - 256]);
    }
#pragma unroll
    for (int t = 0; t < 8; ++t) {
        float4 o = make_float4(acc[t][0] + bv[0], acc[t][1] + bv[1],
                               acc[t][2] + bv[2], acc[t][3] + bv[3]);
        *(float4*)(out + (size_t)(mb + ty * 8 + t) * 384 + col) = o;
    }
}

// --------------------------- Windowed attention ----------------------------
// One block per (window, head). grid (2048, 4), block 256.
__global__ __launch_bounds__(256) void k_attn(
    const float* __restrict__ qkv, const float* __restrict__ rpb,
    const float* __restrict__ ls, float* __restrict__ aout, int shift) {
    __shared__ float qs[49 * 33];
    __shared__ float ks[49 * 33];
    __shared__ float vs[49 * 33];
    __shared__ float sm[49 * 56];
    int wid = blockIdx.x, h = blockIdx.y;
    int b = wid >> 6, wrem = wid & 63;
    int wh = wrem >> 3, wwn = wrem & 7;
    int tid = threadIdx.x;

    // stage q,k,v (49 rows x 32 floats each)
    for (int e = tid; e < 49 * 8 * 3; e += 256) {
        int mtx = e / 392;       // 0=q 1=k 2=v
        int r = e % 392;
        int i = r >> 3, d4 = r & 7;
        int hh = wh * 7 + i / 7, wc = wwn * 7 + i % 7;
        size_t m = (size_t)(b * 3136 + hh * 56 + wc);
        float4 v4 = *(const float4*)(qkv + m * 384 + mtx * 128 + h * 32 + d4 * 4);
        float* dst = (mtx == 0 ? qs : (mtx == 1 ? ks : vs)) + i * 33 + d4 * 4;
        dst[0] = v4.x; dst[1] = v4.y; dst[2] = v4.z; dst[3] = v4.w;
    }
    __syncthreads();

    // cosine-normalize rows; fold logit scale into q
    float scale = expf(fminf(ls[h], 4.6051702f));  // ln(100)
    if (tid < 98) {
        float* row = (tid < 49) ? (qs + tid * 33) : (ks + (tid - 49) * 33);
        float ss = 0.f;
        for (int d = 0; d < 32; ++d) ss += row[d] * row[d];
        float inv = 1.0f / fmaxf(sqrtf(ss), 1e-12f);
        if (tid < 49) inv *= scale;
        for (int d = 0; d < 32; ++d) row[d] *= inv;
    }
    __syncthreads();

    // S = qn @ kn^T + rpb (+ mask)
    const float* rp = rpb + h * 2401;
    for (int e = tid; e < 2401; e += 256) {
        int i = e / 49, j = e % 49;
        const float* qr = qs + i * 33;
        const float* kr = ks + j * 33;
        float s = 0.f;
        for (int d = 0; d < 32; ++d) s = fmaf(qr[d], kr[d], s);
        s += rp[e];
        if (shift) {
            int ri = wh * 7 + i / 7, ci = wwn * 7 + i % 7;
            int rj = wh * 7 + j / 7, cj = wwn * 7 + j % 7;
            int li = region3(ri) * 3 + region3(ci);
            int lj = region3(rj) * 3 + region3(cj);
            if (li != lj) s -= 100.0f;
        }
        sm[i * 56 + j] = s;
    }
    __syncthreads();

    // softmax rows
    if (tid < 49) {
        float* row = sm + tid * 56;
        float mx = -1e30f;
        for (int j = 0; j < 49; ++j) mx = fmaxf(mx, row[j]);
        float sum = 0.f;
        for (int j = 0; j < 49; ++j) { float e2 = expf(row[j] - mx); row[j] = e2; sum += e2; }
        float inv = 1.0f / sum;
        for (int j = 0; j < 49; ++j) row[j] *= inv;
    }
    __syncthreads();

    // O = P @ V
    for (int e = tid; e < 49 * 32; e += 256) {
        int i = e >> 5, d = e & 31;
        const float* pr = sm + i * 56;
        float acc = 0.f;
        for (int j = 0; j < 49; ++j) acc = fmaf(pr[j], vs[j * 33 + d], acc);
        int hh = wh * 7 + i / 7, wc = wwn * 7 + i % 7;
        size_t m = (size_t)(b * 3136 + hh * 56 + wc);
        aout[m * 128 + h * 32 + d] = acc;
    }
}

// ------------------- proj GEMM + roll-back + residual + LN -----------------
// xout[orig(m)] = resid[orig(m)] + LN(ain[m] @ w + pb)
__global__ __launch_bounds__(256) void k_proj_ln(
    const float* __restrict__ ain, const float* __restrict__ w,
    const float* __restrict__ pb, const float* __restrict__ g,
    const float* __restrict__ bt, const float* __restrict__ resid,
    float* __restrict__ xout, int shift) {
    __shared__ float4 xs4[64][32];
    const float* xs = (const float*)xs4;
    int tid = threadIdx.x;
    int mb = blockIdx.x * 64;
#pragma unroll
    for (int it = 0; it < 8; ++it) {
        int e = it * 256 + tid;
        int t = e >> 5, k4 = e & 31;
        xs4[t][k4] = ((const float4*)(ain + (size_t)(mb + t) * 128))[k4];
    }
    __syncthreads();
    int tx = tid & 31, ty = tid >> 5;
    float acc[8][4] = {};
    const float* wp = w + tx * 4;
    const float* xrow = xs + ty * 8 * 128;
#pragma unroll 4
    for (int k = 0; k < 128; ++k) {
        float4 wv = *(const float4*)(wp + (size_t)k * 128);
#pragma unroll
        for (int t = 0; t < 8; ++t) {
            float xa = xrow[t * 128 + k];
            acc[t][0] = fmaf(xa, wv.x, acc[t][0]);
            acc[t][1] = fmaf(xa, wv.y, acc[t][1]);
            acc[t][2] = fmaf(xa, wv.z, acc[t][2]);
            acc[t][3] = fmaf(xa, wv.w, acc[t][3]);
        }
    }
    int col = tx * 4;
    float4 pbv = *(const float4*)(pb + col);
    float4 gv = *(const float4*)(g + col);
    float4 btv = *(const float4*)(bt + col);
#pragma unroll
    for (int t = 0; t < 8; ++t) {
        float a0 = acc[t][0] + pbv.x, a1 = acc[t][1] + pbv.y;
        float a2 = acc[t][2] + pbv.z, a3 = acc[t][3] + pbv.w;
        float s1 = a0 + a1 + a2 + a3;
        float s2 = a0 * a0 + a1 * a1 + a2 * a2 + a3 * a3;
#pragma unroll
        for (int off = 16; off >= 1; off >>= 1) {
            s1 += __shfl_xor(s1, off, 64);
            s2 += __shfl_xor(s2, off, 64);
        }
        float mean = s1 * (1.0f / 128.0f);
        float var = s2 * (1.0f / 128.0f) - mean * mean;
        float rstd = rsqrtf(var + 1e-5f);
        int m = mb + ty * 8 + t;
        int b = m / 3136, r = m % 3136;
        int hh = r / 56, ww = r % 56;
        hh += shift; if (hh >= 56) hh -= 56;
        ww += shift; if (ww >= 56) ww -= 56;
        size_t mo = (size_t)(b * 3136 + hh * 56 + ww) * 128 + col;
        float4 rv = *(const float4*)(resid + mo);
        float4 o;
        o.x = rv.x + (a0 - mean) * rstd * gv.x + btv.x;
        o.y = rv.y + (a1 - mean) * rstd * gv.y + btv.y;
        o.z = rv.z + (a2 - mean) * rstd * gv.z + btv.z;
        o.w = rv.w + (a3 - mean) * rstd * gv.w + btv.w;
        *(float4*)(xout + mo) = o;
    }
}

// --------------------------- MLP fc1 + GELU --------------------------------
__global__ __launch_bounds__(256) void k_mlp1(
    const float* __restrict__ xin, const float* __restrict__ w,
    const float* __restrict__ bias, float* __restrict__ hid) {
    __shared__ float4 xs4[64][32];
    const float* xs = (const float*)xs4;
    int tid = threadIdx.x;
    int mb = blockIdx.x * 64;
    int ncb = blockIdx.y * 128;
#pragma unroll
    for (int it = 0; it < 8; ++it) {
        int e = it * 256 + tid;
        int t = e >> 5, k4 = e & 31;
        xs4[t][k4] = ((const float4*)(xin + (size_t)(mb + t) * 128))[k4];
    }
    __syncthreads();
    int tx = tid & 31, ty = tid >> 5;
    float acc[8][4] = {};
    const float* wp = w + ncb + tx * 4;
    const float* xrow = xs + ty * 8 * 128;
#pragma unroll 4
    for (int k = 0; k < 128; ++k) {
        float4 wv = *(const float4*)(wp + (size_t)k * 512);
#pragma unroll
        for (int t = 0; t < 8; ++t) {
            float xa = xrow[t * 128 + k];
            acc[t][0] = fmaf(xa, wv.x, acc[t][0]);
            acc[t][1] = fmaf(xa, wv.y, acc[t][1]);
            acc[t][2] = fmaf(xa, wv.z, acc[t][2]);
            acc[t][3] = fmaf(xa, wv.w, acc[t][3]);
        }
    }
    int col = ncb + tx * 4;
    float4 bb = *(const float4*)(bias + col);
#pragma unroll
    for (int t = 0; t < 8; ++t) {
        float4 o = make_float4(gelu_f(acc[t][0] + bb.x), gelu_f(acc[t][1] + bb.y),
                               gelu_f(acc[t][2] + bb.z), gelu_f(acc[t][3] + bb.w));
        *(float4*)(hid + (size_t)(mb + ty * 8 + t) * 512 + col) = o;
    }
}

// ---------------- MLP fc2 + residual + LN (in-place on x) ------------------
__global__ __launch_bounds__(256) void k_mlp2_ln(
    const float* __restrict__ hid, const float* __restrict__ w,
    const float* __restrict__ pb, const float* __restrict__ g,
    const float* __restrict__ bt, float* __restrict__ x) {
    __shared__ float4 xs4[64][32];
    const float* xs = (const float*)xs4;
    int tid = threadIdx.x;
    int mb = blockIdx.x * 64;
    int tx = tid & 31, ty = tid >> 5;
    float acc[8][4] = {};
    const float* xrow = xs + ty * 8 * 128;
    for (int kc = 0; kc < 4; ++kc) {
        __syncthreads();
#pragma unroll
        for (int it = 0; it < 8; ++it) {
            int e = it * 256 + tid;
            int t = e >> 5, k4 = e & 31;
            xs4[t][k4] = ((const float4*)(hid + (size_t)(mb + t) * 512 + kc * 128))[k4];
        }
        __syncthreads();
        const float* wp = w + (size_t)kc * 128 * 128 + tx * 4;
#pragma unroll 4
        for (int k = 0; k < 128; ++k) {
            float4 wv = *(const float4*)(wp + (size_t)k * 128);
#pragma unroll
            for (int t = 0; t < 8; ++t) {
                float xa = xrow[t * 128 + k];
                acc[t][0] = fmaf(xa, wv.x, acc[t][0]);
                acc[t][1] = fmaf(xa, wv.y, acc[t][1]);
                acc[t][2] = fmaf(xa, wv.z, acc[t][2]);
                acc[t][3] = fmaf(xa, wv.w, acc[t][3]);
            }
        }
    }
    int col = tx * 4;
    float4 pbv = *(const float4*)(pb + col);
    float4 gv = *(const float4*)(g + col);
    float4 btv = *(const float4*)(bt + col);
#pragma unroll
    for (int t = 0; t < 8; ++t) {
        float a0 = acc[t][0] + pbv.x, a1 = acc[t][1] + pbv.y;
        float a2 = acc[t][2] + pbv.z, a3 = acc[t][3] + pbv.w;
        float s1 = a0 + a1 + a2 + a3;
        float s2 = a0 * a0 + a1 * a1 + a2 * a2 + a3 * a3;
#pragma unroll
        for (int off = 16; off >= 1; off >>= 1) {
            s1 += __shfl_xor(s1, off, 64);
            s2 += __shfl_xor(s2, off, 64);
        }
        float mean = s1 * (1.0f / 128.0f);
        float var = s2 * (1.0f / 128.0f) - mean * mean;
        float rstd = rsqrtf(var + 1e-5f);
        size_t mo = (size_t)(mb + ty * 8 + t) * 128 + col;
        float4 rv = *(const float4*)(x + mo);
        float4 o;
        o.x = rv.x + (a0 - mean) * rstd * gv.x + btv.x;
        o.y = rv.y + (a1 - mean) * rstd * gv.y + btv.y;
        o.z = rv.z + (a2 - mean) * rstd * gv.z + btv.z;
        o.w = rv.w + (a3 - mean) * rstd * gv.w + btv.w;
        *(float4*)(x + mo) = o;
    }
}

// ------------------- PatchMerging: gather + LN + GEMM ----------------------
// 32 output tokens per block; grid 784.
__global__ __launch_bounds__(256) void k_pm(
    const float* __restrict__ x, const float* __restrict__ g,
    const float* __restrict__ bt, const float* __restrict__ w,
    float* __restrict__ out) {
    __shared__ float xs[32 * 516];
    __shared__ float stats[64];
    int tid = threadIdx.x;
    int mb = blockIdx.x * 32;
#pragma unroll
    for (int it = 0; it < 16; ++it) {
        int e = it * 256 + tid;  // 4096 float4
        int t = e >> 7, q = e & 127;
        int m2 = mb + t;
        int b = m2 / 784, r = m2 % 784;
        int h2 = r / 28, w2 = r % 28;
        int i2 = q >> 6, j2 = (q >> 5) & 1, c4 = q & 31;
        float4 v4 = *(const float4*)(
            x + (size_t)((b * 56 + 2 * h2 + i2) * 56 + 2 * w2 + j2) * 128 + c4 * 4);
        *(float4*)(xs + t * 516 + q * 4) = v4;
    }
    __syncthreads();
    if (tid < 32) {
        const float* row = xs + tid * 516;
        float s1 = 0.f, s2 = 0.f;
        for (int c = 0; c < 512; ++c) { float v = row[c]; s1 += v; s2 += v * v; }
        float mean = s1 * (1.0f / 512.0f);
        float var = s2 * (1.0f / 512.0f) - mean * mean;
        stats[tid * 2] = mean;
        stats[tid * 2 + 1] = rsqrtf(var + 1e-5f);
    }
    __syncthreads();
    for (int it = 0; it < 64; ++it) {
        int e = it * 256 + tid;
        int t = e >> 9, c = e & 511;
        float v = xs[t * 516 + c];
        xs[t * 516 + c] = (v - stats[t * 2]) * stats[t * 2 + 1] * g[c] + bt[c];
    }
    __syncthreads();
    int tx = tid & 63, ty = tid >> 6;
    float acc[8][4] = {};
    const float* wp = w + tx * 4;
    const float* xrow = xs + ty * 8 * 516;
    for (int k = 0; k < 512; ++k) {
        float4 wv = *(const float4*)(wp + (size_t)k * 256);
#pragma unroll
        for (int t = 0; t < 8; ++t) {
            float xa = xrow[t * 516 + k];
            acc[t][0] = fmaf(xa, wv.x, acc[t][0]);
            acc[t][1] = fmaf(xa, wv.y, acc[t][1]);
            acc[t][2] = fmaf(xa, wv.z, acc[t][2]);
            acc[t][3] = fmaf(xa, wv.w, acc[t][3]);
        }
    }
#pragma unroll
    for (int t = 0; t < 8; ++t) {
        *(float4*)(out + (size_t)(mb + ty * 8 + t) * 256 + tx * 4) =
            make_float4(acc[t][0], acc[t][1], acc[t][2], acc[t][3]);
    }
}

// ---------------------------------------------------------------------------
extern "C" void kernel_launch(void* const* d_in, const int* in_sizes, int n_in,
                              void* d_out, int out_size, void* d_ws, size_t ws_size,
                              hipStream_t stream) {
    const float* x_in   = (const float*)d_in[0];
    const float* qkv_w  = (const float*)d_in[1];
    const float* q_bias = (const float*)d_in[2];
    const float* v_bias = (const float*)d_in[3];
    const float* lscale = (const float*)d_in[4];
    const float* cpb_w1 = (const float*)d_in[5];
    const float* cpb_b1 = (const float*)d_in[6];
    const float* cpb_w2 = (const float*)d_in[7];
    const float* proj_w = (const float*)d_in[8];
    const float* proj_b = (const float*)d_in[9];
    const float* n1g    = (const float*)d_in[10];
    const float* n1b    = (const float*)d_in[11];
    const float* mw1    = (const float*)d_in[12];
    const float* mb1    = (const float*)d_in[13];
    const float* mw2    = (const float*)d_in[14];
    const float* mb2    = (const float*)d_in[15];
    const float* n2g    = (const float*)d_in[16];
    const float* n2b    = (const float*)d_in[17];
    const float* pmg    = (const float*)d_in[18];
    const float* pmb    = (const float*)d_in[19];
    const float* pmw    = (const float*)d_in[20];
    float* out = (float*)d_out;

    // workspace layout (floats):
    //   xcur   : kTok*128            = 12,845,056
    //   regA   : kTok*512            = 51,380,224  (qkv uses first kTok*384;
    //            attnout packed in regA tail; hid overwrites whole region)
    //   out169 : 704 (padded)
    //   rpb    : 9,604
    float* wsf     = (float*)d_ws;
    float* xcur    = wsf;
    float* regA    = wsf + (size_t)12845056;
    float* attnout = regA + (size_t)kTok * 384;     // tail of regA: kTok*128
    float* out169  = regA + (size_t)kTok * 512;
    float* rpb     = out169 + 704;

    for (int i = 0; i < 2; ++i) {
        int shift = i ? 3 : 0;
        const float* xi = (i == 0) ? x_in : xcur;
        k_cpb<<<169, 256, 0, stream>>>(cpb_w1 + i * 1024, cpb_b1 + i * 512,
                                       cpb_w2 + i * 2048, out169);
        k_rpb<<<38, 256, 0, stream>>>(out169, rpb);
        k_qkv<<<dim3(1568, 3), 256, 0, stream>>>(
            xi, qkv_w + i * 49152, q_bias + i * 128, v_bias + i * 128, regA, shift);
        k_attn<<<dim3(2048, 4), 256, 0, stream>>>(
            regA, rpb, lscale + i * 4, attnout, shift);
        k_proj_ln<<<1568, 256, 0, stream>>>(
            attnout, proj_w + i * 16384, proj_b + i * 128,
            n1g + i * 128, n1b + i * 128, xi, xcur, shift);
        k_mlp1<<<dim3(1568, 4), 256, 0, stream>>>(
            xcur, mw1 + i * 65536, mb1 + i * 512, regA);
        k_mlp2_ln<<<1568, 256, 0, stream>>>(
            regA, mw2 + i * 65536, mb2 + i * 128,
            n2g + i * 128, n2b + i * 128, xcur);
    }
    k_pm<<<784, 256, 0, stream>>>(xcur, pmg, pmb, pmw, out);
}

// Round 2
// 1073.898 us; speedup vs baseline: 1.5287x; 1.5287x over previous
//
#include <hip/hip_runtime.h>
#include <math.h>

// ---------------------------------------------------------------------------
// SwinV2 stage: B=32, H=W=56, C=128, NH=4, hd=32, WS=7, N=49, DEPTH=2, shift=3
// Round 2: all large GEMMs on bf16 MFMA (16x16x32), fused resln pass,
// bf16 qkv/hid, wave-parallel attn softmax/normalize.
// ---------------------------------------------------------------------------

namespace {
constexpr int kTok = 32 * 56 * 56;   // 100352 tokens
}

typedef __attribute__((ext_vector_type(8))) short bf16x8;
typedef __attribute__((ext_vector_type(4))) float f32x4;

__device__ __forceinline__ short f2bf(float f) {
    unsigned u = __float_as_uint(f);
    return (short)((u + 0x7FFFu + ((u >> 16) & 1u)) >> 16);
}
__device__ __forceinline__ float bf2f(unsigned short u) {
    return __uint_as_float(((unsigned)u) << 16);
}
__device__ __forceinline__ float gelu_f(float x) {
    return 0.5f * x * (1.0f + erff(x * 0.70710678118654752f));
}
__device__ __forceinline__ int region3(int r) {
    return (r < 49) ? 0 : ((r < 53) ? 1 : 2);
}

// --------------------------- CPB MLP (tiny) --------------------------------
__global__ __launch_bounds__(256) void k_cpb(
    const float* __restrict__ w1, const float* __restrict__ b1,
    const float* __restrict__ w2, float* __restrict__ out169) {
    int t = blockIdx.x;  // 0..168
    int ia = t / 13, ib = t % 13;
    float r0 = (float)(ia - 6) * (8.0f / 6.0f);
    float s0 = (r0 > 0.f) ? 1.f : (r0 < 0.f ? -1.f : 0.f);
    float t0 = s0 * log2f(fabsf(r0) + 1.0f) * (1.0f / 3.0f);
    float r1 = (float)(ib - 6) * (8.0f / 6.0f);
    float s1 = (r1 > 0.f) ? 1.f : (r1 < 0.f ? -1.f : 0.f);
    float t1 = s1 * log2f(fabsf(r1) + 1.0f) * (1.0f / 3.0f);

    int tid = threadIdx.x;
    float p0 = 0, p1 = 0, p2 = 0, p3 = 0;
    for (int c = tid; c < 512; c += 256) {
        float hv = fmaxf(t0 * w1[c] + t1 * w1[512 + c] + b1[c], 0.0f);
        p0 += hv * w2[c * 4 + 0];
        p1 += hv * w2[c * 4 + 1];
        p2 += hv * w2[c * 4 + 2];
        p3 += hv * w2[c * 4 + 3];
    }
    __shared__ float red[256][4];
    red[tid][0] = p0; red[tid][1] = p1; red[tid][2] = p2; red[tid][3] = p3;
    __syncthreads();
    for (int s = 128; s > 0; s >>= 1) {
        if (tid < s) {
            red[tid][0] += red[tid + s][0];
            red[tid][1] += red[tid + s][1];
            red[tid][2] += red[tid + s][2];
            red[tid][3] += red[tid + s][3];
        }
        __syncthreads();
    }
    if (tid < 4) out169[t * 4 + tid] = red[0][tid];
}

__global__ void k_rpb(const float* __restrict__ out169, float* __restrict__ rpb) {
    int e = blockIdx.x * 256 + threadIdx.x;
    if (e >= 4 * 49 * 49) return;
    int h = e / 2401, r = e % 2401;
    int i = r / 49, j = r % 49;
    int dp = i / 7 - j / 7 + 6;
    int dq = i % 7 - j % 7 + 6;
    float v = out169[(dp * 13 + dq) * 4 + h];
    rpb[e] = 16.0f / (1.0f + expf(-v));
}

// ------------------- weight fp32 -> bf16 tiled image -----------------------
// Layout: slot slt = (nt*Kb + kb)*64 + nn holds W[kb*8+e][nt*64+nn], e=0..7.
__global__ __launch_bounds__(256) void k_cvtw(
    const float* __restrict__ W, short* __restrict__ Wb, int Kb, int N) {
    int slt = blockIdx.x * 256 + threadIdx.x;
    if (slt >= Kb * N) return;
    int nn = slt & 63;
    int tmp = slt >> 6;
    int kb = tmp % Kb;
    int nt = tmp / Kb;
    int n = nt * 64 + nn;
    int k0 = kb * 8;
    union { int4 i4; short s8[8]; } u;
#pragma unroll
    for (int e = 0; e < 8; ++e) u.s8[e] = f2bf(W[(size_t)(k0 + e) * N + n]);
    *(int4*)(Wb + (size_t)slt * 8) = u.i4;
}

// --------------------------- MFMA GEMM -------------------------------------
// C[M x N] = A[M x K] @ W[K x N] (+epilogue). BM=128, BN=64, 4 waves.
// EPI: 0 = raw fp32; 1 = qkv bias -> bf16 out (stride 384), roll on A via shift;
//      2 = bias + gelu -> bf16 out (stride 512).
template <int K, int EPI, bool INBF16>
__global__ __launch_bounds__(256) void k_gemm(
    const void* __restrict__ Ain, const short* __restrict__ Wb,
    const float* __restrict__ bias0, const float* __restrict__ bias1,
    void* __restrict__ Out, int ostride, int shift) {
    constexpr int Kb = K / 8;
    constexpr int NC = K / 128;
    __shared__ int4 As4[2048];  // [16 kb][128 m] slots of 8 bf16, XOR-swizzled
    int tid = threadIdx.x;
    int nt = blockIdx.x, mt = blockIdx.y;
    int mb = mt * 128;
    int w = tid >> 6, l = tid & 63, lr = l & 15, lg = l >> 4;
    const f32x4 fz = {0.f, 0.f, 0.f, 0.f};
    f32x4 acc[2][4];
#pragma unroll
    for (int mi = 0; mi < 2; ++mi)
#pragma unroll
        for (int ni = 0; ni < 4; ++ni) acc[mi][ni] = fz;

    for (int c = 0; c < NC; ++c) {
        if (c) __syncthreads();
#pragma unroll
        for (int it = 0; it < 8; ++it) {
            int s = it * 256 + tid;
            int m = s >> 4, kb = s & 15;
            int gm = mb + m;
            if (EPI == 1) {
                if (shift) {
                    int b = gm / 3136, r = gm % 3136;
                    int hh = r / 56 + shift; if (hh >= 56) hh -= 56;
                    int ww = r % 56 + shift; if (ww >= 56) ww -= 56;
                    gm = b * 3136 + hh * 56 + ww;
                }
            }
            int slot = kb * 128 + ((m & ~7) | ((m ^ kb) & 7));
            if (INBF16) {
                As4[slot] = *(const int4*)((const short*)Ain + (size_t)gm * K + c * 128 + kb * 8);
            } else {
                const float* src = (const float*)Ain + (size_t)gm * K + c * 128 + kb * 8;
                float4 f0 = *(const float4*)src;
                float4 f1 = *(const float4*)(src + 4);
                union { int4 i4; short s8[8]; } u;
                u.s8[0] = f2bf(f0.x); u.s8[1] = f2bf(f0.y);
                u.s8[2] = f2bf(f0.z); u.s8[3] = f2bf(f0.w);
                u.s8[4] = f2bf(f1.x); u.s8[5] = f2bf(f1.y);
                u.s8[6] = f2bf(f1.z); u.s8[7] = f2bf(f1.w);
                As4[slot] = u.i4;
            }
        }
        __syncthreads();
        const short* wbase = Wb + ((size_t)nt * Kb + c * 16) * 64 * 8;
#pragma unroll
        for (int kk = 0; kk < 4; ++kk) {
            int kbl = kk * 4 + lg;
            int m0 = w * 32 + lr;
            bf16x8 a0 = *(const bf16x8*)&As4[kbl * 128 + ((m0 & ~7) | ((m0 ^ kbl) & 7))];
            int m1 = m0 + 16;
            bf16x8 a1 = *(const bf16x8*)&As4[kbl * 128 + ((m1 & ~7) | ((m1 ^ kbl) & 7))];
#pragma unroll
            for (int ni = 0; ni < 4; ++ni) {
                bf16x8 bfr = *(const bf16x8*)(wbase + ((size_t)(kbl * 64 + lr + 16 * ni)) * 8);
                acc[0][ni] = __builtin_amdgcn_mfma_f32_16x16x32_bf16(a0, bfr, acc[0][ni], 0, 0, 0);
                acc[1][ni] = __builtin_amdgcn_mfma_f32_16x16x32_bf16(a1, bfr, acc[1][ni], 0, 0, 0);
            }
        }
    }
    // epilogue: D lane map col=lane&15, row=(lane>>4)*4+reg  [HW-verified]
#pragma unroll
    for (int ni = 0; ni < 4; ++ni) {
        int col = nt * 64 + ni * 16 + lr;
        float bv = 0.f;
        if (EPI == 1) bv = (col < 128) ? bias0[col] : ((col < 256) ? 0.f : bias1[col - 256]);
        if (EPI == 2) bv = bias0[col];
#pragma unroll
        for (int mi = 0; mi < 2; ++mi) {
#pragma unroll
            for (int r = 0; r < 4; ++r) {
                int row = mb + w * 32 + mi * 16 + lg * 4 + r;
                float v = acc[mi][ni][r] + bv;
                if (EPI == 0) {
                    ((float*)Out)[(size_t)row * ostride + col] = v;
                } else if (EPI == 1) {
                    ((short*)Out)[(size_t)row * 384 + col] = f2bf(v);
                } else {
                    ((short*)Out)[(size_t)row * 512 + col] = f2bf(gelu_f(v));
                }
            }
        }
    }
}

// --------------------------- Windowed attention ----------------------------
// One block per (window, head). grid (2048, 4), block 256. qkv input is bf16.
__global__ __launch_bounds__(256) void k_attn(
    const short* __restrict__ qkv, const float* __restrict__ rpb,
    const float* __restrict__ ls, float* __restrict__ aout, int shift) {
    __shared__ float qs[49 * 33];
    __shared__ float ks[49 * 33];
    __shared__ float vs[49 * 33];
    __shared__ float sm[49 * 56];
    int wid = blockIdx.x, h = blockIdx.y;
    int b = wid >> 6, wrem = wid & 63;
    int wh = wrem >> 3, wwn = wrem & 7;
    int tid = threadIdx.x;

    for (int e = tid; e < 588; e += 256) {   // 3 mats * 49 rows * 4 x 8bf16
        int mtx = e / 196, r = e % 196;
        int i = r >> 2, d8 = r & 3;
        int hh = wh * 7 + i / 7, wc = wwn * 7 + i % 7;
        size_t m = (size_t)(b * 3136 + hh * 56 + wc);
        int4 raw4 = *(const int4*)(qkv + m * 384 + mtx * 128 + h * 32 + d8 * 8);
        union { int4 i4; unsigned short u8[8]; } uu; uu.i4 = raw4;
        float* dst = (mtx == 0 ? qs : (mtx == 1 ? ks : vs)) + i * 33 + d8 * 8;
#pragma unroll
        for (int j = 0; j < 8; ++j) dst[j] = bf2f(uu.u8[j]);
    }
    __syncthreads();

    // cosine-normalize rows (4 lanes per row); fold logit scale into q
    float scale = expf(fminf(ls[h], 4.6051702f));  // ln(100)
    {
        int g4 = tid >> 2, l4 = tid & 3;
        for (int rr = g4; rr < 98; rr += 64) {
            float* row = (rr < 49) ? (qs + rr * 33) : (ks + (rr - 49) * 33);
            float ss = 0.f;
            for (int d = l4; d < 32; d += 4) ss += row[d] * row[d];
            ss += __shfl_xor(ss, 1);
            ss += __shfl_xor(ss, 2);
            float inv = 1.0f / fmaxf(sqrtf(ss), 1e-12f);
            if (rr < 49) inv *= scale;
            for (int d = l4; d < 32; d += 4) row[d] *= inv;
        }
    }
    __syncthreads();

    // S = qn @ kn^T + rpb (+ mask)
    const float* rp = rpb + h * 2401;
    for (int e = tid; e < 2401; e += 256) {
        int i = e / 49, j = e % 49;
        const float* qr = qs + i * 33;
        const float* kr = ks + j * 33;
        float s = 0.f;
        for (int d = 0; d < 32; ++d) s = fmaf(qr[d], kr[d], s);
        s += rp[e];
        if (shift) {
            int ri = wh * 7 + i / 7, ci = wwn * 7 + i % 7;
            int rj = wh * 7 + j / 7, cj = wwn * 7 + j % 7;
            int li = region3(ri) * 3 + region3(ci);
            int lj = region3(rj) * 3 + region3(cj);
            if (li != lj) s -= 100.0f;
        }
        sm[i * 56 + j] = s;
    }
    __syncthreads();

    // softmax: 16 lanes per row
    {
        int g16 = tid >> 4, lj = tid & 15;
        for (int i = g16; i < 49; i += 16) {
            float* row = sm + i * 56;
            float mx = -1e30f;
            for (int j = lj; j < 49; j += 16) mx = fmaxf(mx, row[j]);
            mx = fmaxf(mx, __shfl_xor(mx, 8));
            mx = fmaxf(mx, __shfl_xor(mx, 4));
            mx = fmaxf(mx, __shfl_xor(mx, 2));
            mx = fmaxf(mx, __shfl_xor(mx, 1));
            float sum = 0.f;
            for (int j = lj; j < 49; j += 16) {
                float e2 = expf(row[j] - mx); row[j] = e2; sum += e2;
            }
            sum += __shfl_xor(sum, 8);
            sum += __shfl_xor(sum, 4);
            sum += __shfl_xor(sum, 2);
            sum += __shfl_xor(sum, 1);
            float inv = 1.0f / sum;
            for (int j = lj; j < 49; j += 16) row[j] *= inv;
        }
    }
    __syncthreads();

    // O = P @ V
    for (int e = tid; e < 49 * 32; e += 256) {
        int i = e >> 5, d = e & 31;
        const float* pr = sm + i * 56;
        float acc = 0.f;
        for (int j = 0; j < 49; ++j) acc = fmaf(pr[j], vs[j * 33 + d], acc);
        int hh = wh * 7 + i / 7, wc = wwn * 7 + i % 7;
        size_t m = (size_t)(b * 3136 + hh * 56 + wc);
        aout[m * 128 + h * 32 + d] = acc;
    }
}

// ------------------- fused bias + LN + residual (+roll-back) ---------------
// xout[mo] = resid[mo] + LN(raw[token] + bias),  mo = rolled-back(token)
__global__ __launch_bounds__(256) void k_resln(
    const float* __restrict__ raw, const float* __restrict__ bias,
    const float* __restrict__ g, const float* __restrict__ bt,
    const float* __restrict__ resid, float* __restrict__ xout, int shift) {
    int token = blockIdx.x * 4 + (threadIdx.x >> 6);
    int l = threadIdx.x & 63;
    float2 rv = *(const float2*)(raw + (size_t)token * 128 + l * 2);
    float a0 = rv.x + bias[2 * l];
    float a1 = rv.y + bias[2 * l + 1];
    float s1 = a0 + a1, s2 = a0 * a0 + a1 * a1;
#pragma unroll
    for (int off = 32; off >= 1; off >>= 1) {
        s1 += __shfl_xor(s1, off);
        s2 += __shfl_xor(s2, off);
    }
    float mean = s1 * (1.0f / 128.0f);
    float var = s2 * (1.0f / 128.0f) - mean * mean;
    float rstd = rsqrtf(var + 1e-5f);
    int mo = token;
    if (shift) {
        int b = token / 3136, r = token % 3136;
        int hh = r / 56 + shift; if (hh >= 56) hh -= 56;
        int ww = r % 56 + shift; if (ww >= 56) ww -= 56;
        mo = b * 3136 + hh * 56 + ww;
    }
    float2 res = *(const float2*)(resid + (size_t)mo * 128 + l * 2);
    float2 o;
    o.x = res.x + (a0 - mean) * rstd * g[2 * l] + bt[2 * l];
    o.y = res.y + (a1 - mean) * rstd * g[2 * l + 1] + bt[2 * l + 1];
    *(float2*)(xout + (size_t)mo * 128 + l * 2) = o;
}

// ------------------- PatchMerging: gather + LN + GEMM (fp32) ---------------
__global__ __launch_bounds__(256) void k_pm(
    const float* __restrict__ x, const float* __restrict__ g,
    const float* __restrict__ bt, const float* __restrict__ w,
    float* __restrict__ out) {
    __shared__ float xs[32 * 516];
    __shared__ float stats[64];
    int tid = threadIdx.x;
    int mb = blockIdx.x * 32;
#pragma unroll
    for (int it = 0; it < 16; ++it) {
        int e = it * 256 + tid;  // 4096 float4
        int t = e >> 7, q = e & 127;
        int m2 = mb + t;
        int b = m2 / 784, r = m2 % 784;
        int h2 = r / 28, w2 = r % 28;
        int i2 = q >> 6, j2 = (q >> 5) & 1, c4 = q & 31;
        float4 v4 = *(const float4*)(
            x + (size_t)((b * 56 + 2 * h2 + i2) * 56 + 2 * w2 + j2) * 128 + c4 * 4);
        *(float4*)(xs + t * 516 + q * 4) = v4;
    }
    __syncthreads();
    if (tid < 32) {
        const float* row = xs + tid * 516;
        float s1 = 0.f, s2 = 0.f;
        for (int c = 0; c < 512; ++c) { float v = row[c]; s1 += v; s2 += v * v; }
        float mean = s1 * (1.0f / 512.0f);
        float var = s2 * (1.0f / 512.0f) - mean * mean;
        stats[tid * 2] = mean;
        stats[tid * 2 + 1] = rsqrtf(var + 1e-5f);
    }
    __syncthreads();
    for (int it = 0; it < 64; ++it) {
        int e = it * 256 + tid;
        int t = e >> 9, c = e & 511;
        float v = xs[t * 516 + c];
        xs[t * 516 + c] = (v - stats[t * 2]) * stats[t * 2 + 1] * g[c] + bt[c];
    }
    __syncthreads();
    int tx = tid & 63, ty = tid >> 6;
    float acc[8][4] = {};
    const float* wp = w + tx * 4;
    const float* xrow = xs + ty * 8 * 516;
    for (int k = 0; k < 512; ++k) {
        float4 wv = *(const float4*)(wp + (size_t)k * 256);
#pragma unroll
        for (int t = 0; t < 8; ++t) {
            float xa = xrow[t * 516 + k];
            acc[t][0] = fmaf(xa, wv.x, acc[t][0]);
            acc[t][1] = fmaf(xa, wv.y, acc[t][1]);
            acc[t][2] = fmaf(xa, wv.z, acc[t][2]);
            acc[t][3] = fmaf(xa, wv.w, acc[t][3]);
        }
    }
#pragma unroll
    for (int t = 0; t < 8; ++t) {
        *(float4*)(out + (size_t)(mb + ty * 8 + t) * 256 + tx * 4) =
            make_float4(acc[t][0], acc[t][1], acc[t][2], acc[t][3]);
    }
}

// ---------------------------------------------------------------------------
extern "C" void kernel_launch(void* const* d_in, const int* in_sizes, int n_in,
                              void* d_out, int out_size, void* d_ws, size_t ws_size,
                              hipStream_t stream) {
    const float* x_in   = (const float*)d_in[0];
    const float* qkv_w  = (const float*)d_in[1];
    const float* q_bias = (const float*)d_in[2];
    const float* v_bias = (const float*)d_in[3];
    const float* lscale = (const float*)d_in[4];
    const float* cpb_w1 = (const float*)d_in[5];
    const float* cpb_b1 = (const float*)d_in[6];
    const float* cpb_w2 = (const float*)d_in[7];
    const float* proj_w = (const float*)d_in[8];
    const float* proj_b = (const float*)d_in[9];
    const float* n1g    = (const float*)d_in[10];
    const float* n1b    = (const float*)d_in[11];
    const float* mw1    = (const float*)d_in[12];
    const float* mb1    = (const float*)d_in[13];
    const float* mw2    = (const float*)d_in[14];
    const float* mb2    = (const float*)d_in[15];
    const float* n2g    = (const float*)d_in[16];
    const float* n2b    = (const float*)d_in[17];
    const float* pmg    = (const float*)d_in[18];
    const float* pmb    = (const float*)d_in[19];
    const float* pmw    = (const float*)d_in[20];
    float* out = (float*)d_out;

    // workspace layout (floats):
    //  xcur 12,845,056 | R1 38,535,168 | wbf 98,304 | out169 704 | rpb 9,604
    //  R1 overlays (stream-ordered lifetimes):
    //   qkvb bf16 [0,19.27M) -> attnout f32 [19.27M,32.11M) -> raw1 f32 [0,12.85M)
    //   -> hid bf16 [0,25.69M) -> raw2 f32 [25.69M,38.54M)
    float* wsf     = (float*)d_ws;
    float* xcur    = wsf;
    float* R1      = wsf + (size_t)12845056;
    short* qkvb    = (short*)R1;
    float* attnout = R1 + (size_t)19267584;
    float* raw1    = R1;
    short* hid     = (short*)R1;
    float* raw2    = R1 + (size_t)25690112;
    float* wtail   = R1 + (size_t)38535168;
    short* wqkvb   = (short*)wtail;          // 49,152 bf16
    short* wprojb  = wqkvb + 49152;          // 16,384
    short* wm1b    = wprojb + 16384;         // 65,536
    short* wm2b    = wm1b + 65536;           // 65,536
    float* out169  = wtail + 98304 / 2 + 49152;  // = wtail + 98304 floats? no:
    // (196,608 shorts == 98,304 floats)
    out169 = wtail + 98304;
    float* rpb = out169 + 704;

    for (int i = 0; i < 2; ++i) {
        int shift = i ? 3 : 0;
        const float* xi = (i == 0) ? x_in : xcur;
        k_cpb<<<169, 256, 0, stream>>>(cpb_w1 + i * 1024, cpb_b1 + i * 512,
                                       cpb_w2 + i * 2048, out169);
        k_rpb<<<38, 256, 0, stream>>>(out169, rpb);
        k_cvtw<<<24, 256, 0, stream>>>(qkv_w + i * 49152, wqkvb, 16, 384);
        k_cvtw<<<8, 256, 0, stream>>>(proj_w + i * 16384, wprojb, 16, 128);
        k_cvtw<<<32, 256, 0, stream>>>(mw1 + i * 65536, wm1b, 16, 512);
        k_cvtw<<<32, 256, 0, stream>>>(mw2 + i * 65536, wm2b, 64, 128);

        k_gemm<128, 1, false><<<dim3(6, 784), 256, 0, stream>>>(
            xi, wqkvb, q_bias + i * 128, v_bias + i * 128, qkvb, 384, shift);
        k_attn<<<dim3(2048, 4), 256, 0, stream>>>(
            qkvb, rpb, lscale + i * 4, attnout, shift);
        k_gemm<128, 0, false><<<dim3(2, 784), 256, 0, stream>>>(
            attnout, wprojb, nullptr, nullptr, raw1, 128, 0);
        k_resln<<<25088, 256, 0, stream>>>(
            raw1, proj_b + i * 128, n1g + i * 128, n1b + i * 128, xi, xcur, shift);
        k_gemm<128, 2, false><<<dim3(8, 784), 256, 0, stream>>>(
            xcur, wm1b, mb1 + i * 512, nullptr, hid, 512, 0);
        k_gemm<512, 0, true><<<dim3(2, 784), 256, 0, stream>>>(
            hid, wm2b, nullptr, nullptr, raw2, 128, 0);
        k_resln<<<25088, 256, 0, stream>>>(
            raw2, mb2 + i * 128, n2g + i * 128, n2b + i * 128, xcur, xcur, 0);
    }
    k_pm<<<784, 256, 0, stream>>>(xcur, pmg, pmb, pmw, out);
}

// Round 3
// 853.942 us; speedup vs baseline: 1.9225x; 1.2576x over previous
//
#include <hip/hip_runtime.h>
#include <math.h>

// ---------------------------------------------------------------------------
// SwinV2 stage: B=32, H=W=56, C=128, NH=4, hd=32, WS=7, N=49, DEPTH=2, shift=3
// Round 3: MFMA attention (swapped QK^T, in-register softmax, LDS P/Vt),
// bf16 attnout, all big GEMMs on MFMA.
// ---------------------------------------------------------------------------

namespace {
constexpr int kTok = 32 * 56 * 56;   // 100352 tokens
}

typedef __attribute__((ext_vector_type(8))) short bf16x8;
typedef __attribute__((ext_vector_type(4))) float f32x4;

union FragU {
    int4 i4;
    bf16x8 b8;
    unsigned short u[8];
};

__device__ __forceinline__ short f2bf(float f) {
    unsigned u = __float_as_uint(f);
    return (short)((u + 0x7FFFu + ((u >> 16) & 1u)) >> 16);
}
__device__ __forceinline__ float bf2f(unsigned short u) {
    return __uint_as_float(((unsigned)u) << 16);
}
__device__ __forceinline__ float gelu_f(float x) {
    return 0.5f * x * (1.0f + erff(x * 0.70710678118654752f));
}

// --------------------------- CPB MLP (tiny) --------------------------------
__global__ __launch_bounds__(256) void k_cpb(
    const float* __restrict__ w1, const float* __restrict__ b1,
    const float* __restrict__ w2, float* __restrict__ out169) {
    int t = blockIdx.x;  // 0..168
    int ia = t / 13, ib = t % 13;
    float r0 = (float)(ia - 6) * (8.0f / 6.0f);
    float s0 = (r0 > 0.f) ? 1.f : (r0 < 0.f ? -1.f : 0.f);
    float t0 = s0 * log2f(fabsf(r0) + 1.0f) * (1.0f / 3.0f);
    float r1 = (float)(ib - 6) * (8.0f / 6.0f);
    float s1 = (r1 > 0.f) ? 1.f : (r1 < 0.f ? -1.f : 0.f);
    float t1 = s1 * log2f(fabsf(r1) + 1.0f) * (1.0f / 3.0f);

    int tid = threadIdx.x;
    float p0 = 0, p1 = 0, p2 = 0, p3 = 0;
    for (int c = tid; c < 512; c += 256) {
        float hv = fmaxf(t0 * w1[c] + t1 * w1[512 + c] + b1[c], 0.0f);
        p0 += hv * w2[c * 4 + 0];
        p1 += hv * w2[c * 4 + 1];
        p2 += hv * w2[c * 4 + 2];
        p3 += hv * w2[c * 4 + 3];
    }
    __shared__ float red[256][4];
    red[tid][0] = p0; red[tid][1] = p1; red[tid][2] = p2; red[tid][3] = p3;
    __syncthreads();
    for (int s = 128; s > 0; s >>= 1) {
        if (tid < s) {
            red[tid][0] += red[tid + s][0];
            red[tid][1] += red[tid + s][1];
            red[tid][2] += red[tid + s][2];
            red[tid][3] += red[tid + s][3];
        }
        __syncthreads();
    }
    if (tid < 4) out169[t * 4 + tid] = red[0][tid];
}

// rpb64[h][qrow64][krow64]; krow>=49 -> -30000 (k-pad baked in)
__global__ void k_rpb(const float* __restrict__ out169, float* __restrict__ rpb64) {
    int e = blockIdx.x * 256 + threadIdx.x;
    if (e >= 4 * 64 * 64) return;
    int h = e >> 12, r = e & 4095;
    int i = r >> 6, j = r & 63;
    float val;
    if (j >= 49) {
        val = -30000.0f;
    } else if (i >= 49) {
        val = 0.0f;
    } else {
        int dp = i / 7 - j / 7 + 6;
        int dq = i % 7 - j % 7 + 6;
        float v = out169[(dp * 13 + dq) * 4 + h];
        val = 16.0f / (1.0f + expf(-v));
    }
    rpb64[e] = val;
}

// ------------------- weight fp32 -> bf16 tiled image -----------------------
// slot slt = (nt*Kb + kb)*64 + nn holds W[kb*8+e][nt*64+nn], e=0..7.
__global__ __launch_bounds__(256) void k_cvtw(
    const float* __restrict__ W, short* __restrict__ Wb, int Kb, int N) {
    int slt = blockIdx.x * 256 + threadIdx.x;
    if (slt >= Kb * N) return;
    int nn = slt & 63;
    int tmp = slt >> 6;
    int kb = tmp % Kb;
    int nt = tmp / Kb;
    int n = nt * 64 + nn;
    int k0 = kb * 8;
    union { int4 i4; short s8[8]; } u;
#pragma unroll
    for (int e = 0; e < 8; ++e) u.s8[e] = f2bf(W[(size_t)(k0 + e) * N + n]);
    *(int4*)(Wb + (size_t)slt * 8) = u.i4;
}

// --------------------------- MFMA GEMM -------------------------------------
// C[M x N] = A[M x K] @ W[K x N] (+epilogue). BM=128, BN=64, 4 waves.
// EPI: 0 = raw fp32; 1 = qkv bias -> bf16 out (stride 384), roll on A;
//      2 = bias + gelu -> bf16 out (stride 512).
template <int K, int EPI, bool INBF16>
__global__ __launch_bounds__(256) void k_gemm(
    const void* __restrict__ Ain, const short* __restrict__ Wb,
    const float* __restrict__ bias0, const float* __restrict__ bias1,
    void* __restrict__ Out, int ostride, int shift) {
    constexpr int Kb = K / 8;
    constexpr int NC = K / 128;
    __shared__ int4 As4[2048];  // [16 kb][128 m], XOR-swizzled
    int tid = threadIdx.x;
    int nt = blockIdx.x, mt = blockIdx.y;
    int mb = mt * 128;
    int w = tid >> 6, l = tid & 63, lr = l & 15, lg = l >> 4;
    const f32x4 fz = {0.f, 0.f, 0.f, 0.f};
    f32x4 acc[2][4];
#pragma unroll
    for (int mi = 0; mi < 2; ++mi)
#pragma unroll
        for (int ni = 0; ni < 4; ++ni) acc[mi][ni] = fz;

    for (int c = 0; c < NC; ++c) {
        if (c) __syncthreads();
#pragma unroll
        for (int it = 0; it < 8; ++it) {
            int s = it * 256 + tid;
            int m = s >> 4, kb = s & 15;
            int gm = mb + m;
            if (EPI == 1) {
                if (shift) {
                    int b = gm / 3136, r = gm % 3136;
                    int hh = r / 56 + shift; if (hh >= 56) hh -= 56;
                    int ww = r % 56 + shift; if (ww >= 56) ww -= 56;
                    gm = b * 3136 + hh * 56 + ww;
                }
            }
            int slot = kb * 128 + ((m & ~7) | ((m ^ kb) & 7));
            if (INBF16) {
                As4[slot] = *(const int4*)((const short*)Ain + (size_t)gm * K + c * 128 + kb * 8);
            } else {
                const float* src = (const float*)Ain + (size_t)gm * K + c * 128 + kb * 8;
                float4 f0 = *(const float4*)src;
                float4 f1 = *(const float4*)(src + 4);
                union { int4 i4; short s8[8]; } u;
                u.s8[0] = f2bf(f0.x); u.s8[1] = f2bf(f0.y);
                u.s8[2] = f2bf(f0.z); u.s8[3] = f2bf(f0.w);
                u.s8[4] = f2bf(f1.x); u.s8[5] = f2bf(f1.y);
                u.s8[6] = f2bf(f1.z); u.s8[7] = f2bf(f1.w);
                As4[slot] = u.i4;
            }
        }
        __syncthreads();
        const short* wbase = Wb + ((size_t)nt * Kb + c * 16) * 64 * 8;
#pragma unroll
        for (int kk = 0; kk < 4; ++kk) {
            int kbl = kk * 4 + lg;
            int m0 = w * 32 + lr;
            bf16x8 a0 = *(const bf16x8*)&As4[kbl * 128 + ((m0 & ~7) | ((m0 ^ kbl) & 7))];
            int m1 = m0 + 16;
            bf16x8 a1 = *(const bf16x8*)&As4[kbl * 128 + ((m1 & ~7) | ((m1 ^ kbl) & 7))];
#pragma unroll
            for (int ni = 0; ni < 4; ++ni) {
                bf16x8 bfr = *(const bf16x8*)(wbase + ((size_t)(kbl * 64 + lr + 16 * ni)) * 8);
                acc[0][ni] = __builtin_amdgcn_mfma_f32_16x16x32_bf16(a0, bfr, acc[0][ni], 0, 0, 0);
                acc[1][ni] = __builtin_amdgcn_mfma_f32_16x16x32_bf16(a1, bfr, acc[1][ni], 0, 0, 0);
            }
        }
    }
#pragma unroll
    for (int ni = 0; ni < 4; ++ni) {
        int col = nt * 64 + ni * 16 + lr;
        float bv = 0.f;
        if (EPI == 1) bv = (col < 128) ? bias0[col] : ((col < 256) ? 0.f : bias1[col - 256]);
        if (EPI == 2) bv = bias0[col];
#pragma unroll
        for (int mi = 0; mi < 2; ++mi) {
#pragma unroll
            for (int r = 0; r < 4; ++r) {
                int row = mb + w * 32 + mi * 16 + lg * 4 + r;
                float v = acc[mi][ni][r] + bv;
                if (EPI == 0) {
                    ((float*)Out)[(size_t)row * ostride + col] = v;
                } else if (EPI == 1) {
                    ((short*)Out)[(size_t)row * 384 + col] = f2bf(v);
                } else {
                    ((short*)Out)[(size_t)row * 512 + col] = f2bf(gelu_f(v));
                }
            }
        }
    }
}

// --------------------------- MFMA windowed attention -----------------------
// grid 2048 (one block per window), 4 waves = 4 heads. qkv bf16 in,
// attnout bf16 out. S^T = mfma(K,Q): lane owns one q-row per col-tile.
__global__ __launch_bounds__(256) void k_attn(
    const short* __restrict__ qkv, const float* __restrict__ rpb64,
    const float* __restrict__ ls, short* __restrict__ aout, int shift) {
    // per wave: P [64][72] bf16 (4608) + Vt [32][72] bf16 (2304)
    __shared__ short lds[4 * 6912];
    int wid = blockIdx.x;
    int b = wid >> 6, wrem = wid & 63;
    int wh = wrem >> 3, ww_ = wrem & 7;
    int h = threadIdx.x >> 6;
    int l = threadIdx.x & 63, lr = l & 15, lg = l >> 4;
    short* Pl = lds + h * 6912;
    short* Vt = Pl + 4608;
    int tokbase = b * 3136 + wh * 7 * 56 + ww_ * 7;

    // ---- load Q,K fragments direct from global; normalize in-register ----
    float scale = __expf(fminf(ls[h], 4.6051702f));  // ln(100)
    int4 qf[4], kf[4];
    const int4 zero4 = make_int4(0, 0, 0, 0);
#pragma unroll
    for (int t = 0; t < 4; ++t) {
        int i = t * 16 + lr;
        bool valid = (i < 49);
        int tok = tokbase + (i / 7) * 56 + (i % 7);
        const short* base = qkv + (size_t)tok * 384 + h * 32 + lg * 8;
        qf[t] = valid ? *(const int4*)base : zero4;
        kf[t] = valid ? *(const int4*)(base + 128) : zero4;
    }
#pragma unroll
    for (int t = 0; t < 4; ++t) {
#pragma unroll
        for (int m = 0; m < 2; ++m) {   // m=0: q, m=1: k
            FragU u; u.i4 = m ? kf[t] : qf[t];
            float x[8], ss = 0.f;
#pragma unroll
            for (int e = 0; e < 8; ++e) { x[e] = bf2f(u.u[e]); ss = fmaf(x[e], x[e], ss); }
            ss += __shfl_xor(ss, 16);
            ss += __shfl_xor(ss, 32);
            float inv = 1.0f / fmaxf(sqrtf(ss), 1e-12f);
            if (m == 0) inv *= scale;
#pragma unroll
            for (int e = 0; e < 8; ++e) u.u[e] = (unsigned short)f2bf(x[e] * inv);
            if (m) kf[t] = u.i4; else qf[t] = u.i4;
        }
    }

    // ---- stage V transposed into LDS (Vt[d][j], stride 72) ----
    // pad cols j=49..63 zeroed (avoid NaN from stale LDS)
    for (int t = l; t < 480; t += 64) {
        Vt[(t / 15) * 72 + 49 + (t % 15)] = 0;
    }
    for (int t = l; t < 196; t += 64) {
        int j = t >> 2, dq = t & 3;
        int tok = tokbase + (j / 7) * 56 + (j % 7);
        FragU u;
        u.i4 = *(const int4*)(qkv + (size_t)tok * 384 + 256 + h * 32 + dq * 8);
#pragma unroll
        for (int e = 0; e < 8; ++e) Vt[(dq * 8 + e) * 72 + j] = (short)u.u[e];
    }

    // ---- S^T = Kn @ Qn^T : acc[qt][jt], col=qrow=qt*16+lr, row=j=jt*16+lg*4+r
    const f32x4 fz = {0.f, 0.f, 0.f, 0.f};
    f32x4 acc[4][4];
#pragma unroll
    for (int qt = 0; qt < 4; ++qt)
#pragma unroll
        for (int jt = 0; jt < 4; ++jt) acc[qt][jt] = fz;
#pragma unroll
    for (int jt = 0; jt < 4; ++jt) {
        FragU a; a.i4 = kf[jt];
#pragma unroll
        for (int qt = 0; qt < 4; ++qt) {
            FragU bq; bq.i4 = qf[qt];
            acc[qt][jt] = __builtin_amdgcn_mfma_f32_16x16x32_bf16(a.b8, bq.b8, acc[qt][jt], 0, 0, 0);
        }
    }

    // ---- + rpb (k-pad baked) + shift mask; softmax per q-row; pack P ----
    bool edge = (shift != 0) && ((wh == 7) || (ww_ == 7));
    const float* rbase = rpb64 + h * 4096;
#pragma unroll
    for (int qt = 0; qt < 4; ++qt) {
        int qi = qt * 16 + lr;
        int qc = (qi < 49) ? qi : 48;
        int rlq = 0, clq = 0;
        if (edge) {
            rlq = (wh == 7) ? ((qc / 7) < 4 ? 1 : 2) : 0;
            clq = (ww_ == 7) ? ((qc % 7) < 4 ? 1 : 2) : 0;
        }
#pragma unroll
        for (int jt = 0; jt < 4; ++jt) {
            float4 rv = *(const float4*)(rbase + qc * 64 + jt * 16 + lg * 4);
            float rr[4] = {rv.x, rv.y, rv.z, rv.w};
#pragma unroll
            for (int r = 0; r < 4; ++r) {
                float v = acc[qt][jt][r] + rr[r];
                if (edge) {
                    int j = jt * 16 + lg * 4 + r;
                    int jc = (j < 49) ? j : 48;
                    int rlk = (wh == 7) ? ((jc / 7) < 4 ? 1 : 2) : 0;
                    int clk = (ww_ == 7) ? ((jc % 7) < 4 ? 1 : 2) : 0;
                    if (rlk != rlq || clk != clq) v -= 100.0f;
                }
                acc[qt][jt][r] = v;
            }
        }
        // softmax over j for this lane's q-row
        float m = -1e30f;
#pragma unroll
        for (int jt = 0; jt < 4; ++jt)
#pragma unroll
            for (int r = 0; r < 4; ++r) m = fmaxf(m, acc[qt][jt][r]);
        m = fmaxf(m, __shfl_xor(m, 16));
        m = fmaxf(m, __shfl_xor(m, 32));
        float s = 0.f;
#pragma unroll
        for (int jt = 0; jt < 4; ++jt)
#pragma unroll
            for (int r = 0; r < 4; ++r) {
                float p = __expf(acc[qt][jt][r] - m);
                acc[qt][jt][r] = p;
                s += p;
            }
        s += __shfl_xor(s, 16);
        s += __shfl_xor(s, 32);
        float inv = 1.0f / s;
        int prow = (qt * 16 + lr) * 72;
#pragma unroll
        for (int jt = 0; jt < 4; ++jt) {
            unsigned lo = (unsigned)(unsigned short)f2bf(acc[qt][jt][0] * inv) |
                          ((unsigned)(unsigned short)f2bf(acc[qt][jt][1] * inv) << 16);
            unsigned hi = (unsigned)(unsigned short)f2bf(acc[qt][jt][2] * inv) |
                          ((unsigned)(unsigned short)f2bf(acc[qt][jt][3] * inv) << 16);
            *(int2*)&Pl[prow + jt * 16 + lg * 4] = make_int2((int)lo, (int)hi);
        }
    }

    // ---- out^T = V^T @ P^T : A=Vt-frag, B=P-frag (both contiguous b128) ----
    f32x4 oacc[2][4];
#pragma unroll
    for (int mi = 0; mi < 2; ++mi)
#pragma unroll
        for (int ni = 0; ni < 4; ++ni) oacc[mi][ni] = fz;
#pragma unroll
    for (int kc = 0; kc < 2; ++kc) {
        FragU va[2], pb[4];
#pragma unroll
        for (int mi = 0; mi < 2; ++mi)
            va[mi].i4 = *(const int4*)&Vt[(mi * 16 + lr) * 72 + kc * 32 + lg * 8];
#pragma unroll
        for (int ni = 0; ni < 4; ++ni)
            pb[ni].i4 = *(const int4*)&Pl[(ni * 16 + lr) * 72 + kc * 32 + lg * 8];
#pragma unroll
        for (int mi = 0; mi < 2; ++mi)
#pragma unroll
            for (int ni = 0; ni < 4; ++ni)
                oacc[mi][ni] = __builtin_amdgcn_mfma_f32_16x16x32_bf16(
                    va[mi].b8, pb[ni].b8, oacc[mi][ni], 0, 0, 0);
    }

    // store: qrow=ni*16+lr, d=mi*16+lg*4+r -> pack 4 bf16 (8B)
#pragma unroll
    for (int ni = 0; ni < 4; ++ni) {
        int qrow = ni * 16 + lr;
        if (qrow < 49) {
            int tok = tokbase + (qrow / 7) * 56 + (qrow % 7);
#pragma unroll
            for (int mi = 0; mi < 2; ++mi) {
                unsigned lo = (unsigned)(unsigned short)f2bf(oacc[mi][ni][0]) |
                              ((unsigned)(unsigned short)f2bf(oacc[mi][ni][1]) << 16);
                unsigned hi = (unsigned)(unsigned short)f2bf(oacc[mi][ni][2]) |
                              ((unsigned)(unsigned short)f2bf(oacc[mi][ni][3]) << 16);
                *(int2*)&aout[(size_t)tok * 128 + h * 32 + mi * 16 + lg * 4] =
                    make_int2((int)lo, (int)hi);
            }
        }
    }
}

// ------------------- fused bias + LN + residual (+roll-back) ---------------
__global__ __launch_bounds__(256) void k_resln(
    const float* __restrict__ raw, const float* __restrict__ bias,
    const float* __restrict__ g, const float* __restrict__ bt,
    const float* __restrict__ resid, float* __restrict__ xout, int shift) {
    int token = blockIdx.x * 4 + (threadIdx.x >> 6);
    int l = threadIdx.x & 63;
    float2 rv = *(const float2*)(raw + (size_t)token * 128 + l * 2);
    float a0 = rv.x + bias[2 * l];
    float a1 = rv.y + bias[2 * l + 1];
    float s1 = a0 + a1, s2 = a0 * a0 + a1 * a1;
#pragma unroll
    for (int off = 32; off >= 1; off >>= 1) {
        s1 += __shfl_xor(s1, off);
        s2 += __shfl_xor(s2, off);
    }
    float mean = s1 * (1.0f / 128.0f);
    float var = s2 * (1.0f / 128.0f) - mean * mean;
    float rstd = rsqrtf(var + 1e-5f);
    int mo = token;
    if (shift) {
        int b = token / 3136, r = token % 3136;
        int hh = r / 56 + shift; if (hh >= 56) hh -= 56;
        int ww = r % 56 + shift; if (ww >= 56) ww -= 56;
        mo = b * 3136 + hh * 56 + ww;
    }
    float2 res = *(const float2*)(resid + (size_t)mo * 128 + l * 2);
    float2 o;
    o.x = res.x + (a0 - mean) * rstd * g[2 * l] + bt[2 * l];
    o.y = res.y + (a1 - mean) * rstd * g[2 * l + 1] + bt[2 * l + 1];
    *(float2*)(xout + (size_t)mo * 128 + l * 2) = o;
}

// ------------------- PatchMerging: gather + LN + GEMM (fp32) ---------------
__global__ __launch_bounds__(256) void k_pm(
    const float* __restrict__ x, const float* __restrict__ g,
    const float* __restrict__ bt, const float* __restrict__ w,
    float* __restrict__ out) {
    __shared__ float xs[32 * 516];
    __shared__ float stats[64];
    int tid = threadIdx.x;
    int mb = blockIdx.x * 32;
#pragma unroll
    for (int it = 0; it < 16; ++it) {
        int e = it * 256 + tid;
        int t = e >> 7, q = e & 127;
        int m2 = mb + t;
        int b = m2 / 784, r = m2 % 784;
        int h2 = r / 28, w2 = r % 28;
        int i2 = q >> 6, j2 = (q >> 5) & 1, c4 = q & 31;
        float4 v4 = *(const float4*)(
            x + (size_t)((b * 56 + 2 * h2 + i2) * 56 + 2 * w2 + j2) * 128 + c4 * 4);
        *(float4*)(xs + t * 516 + q * 4) = v4;
    }
    __syncthreads();
    if (tid < 32) {
        const float* row = xs + tid * 516;
        float s1 = 0.f, s2 = 0.f;
        for (int c = 0; c < 512; ++c) { float v = row[c]; s1 += v; s2 += v * v; }
        float mean = s1 * (1.0f / 512.0f);
        float var = s2 * (1.0f / 512.0f) - mean * mean;
        stats[tid * 2] = mean;
        stats[tid * 2 + 1] = rsqrtf(var + 1e-5f);
    }
    __syncthreads();
    for (int it = 0; it < 64; ++it) {
        int e = it * 256 + tid;
        int t = e >> 9, c = e & 511;
        float v = xs[t * 516 + c];
        xs[t * 516 + c] = (v - stats[t * 2]) * stats[t * 2 + 1] * g[c] + bt[c];
    }
    __syncthreads();
    int tx = tid & 63, ty = tid >> 6;
    float acc[8][4] = {};
    const float* wp = w + tx * 4;
    const float* xrow = xs + ty * 8 * 516;
    for (int k = 0; k < 512; ++k) {
        float4 wv = *(const float4*)(wp + (size_t)k * 256);
#pragma unroll
        for (int t = 0; t < 8; ++t) {
            float xa = xrow[t * 516 + k];
            acc[t][0] = fmaf(xa, wv.x, acc[t][0]);
            acc[t][1] = fmaf(xa, wv.y, acc[t][1]);
            acc[t][2] = fmaf(xa, wv.z, acc[t][2]);
            acc[t][3] = fmaf(xa, wv.w, acc[t][3]);
        }
    }
#pragma unroll
    for (int t = 0; t < 8; ++t) {
        *(float4*)(out + (size_t)(mb + ty * 8 + t) * 256 + tx * 4) =
            make_float4(acc[t][0], acc[t][1], acc[t][2], acc[t][3]);
    }
}

// ---------------------------------------------------------------------------
extern "C" void kernel_launch(void* const* d_in, const int* in_sizes, int n_in,
                              void* d_out, int out_size, void* d_ws, size_t ws_size,
                              hipStream_t stream) {
    const float* x_in   = (const float*)d_in[0];
    const float* qkv_w  = (const float*)d_in[1];
    const float* q_bias = (const float*)d_in[2];
    const float* v_bias = (const float*)d_in[3];
    const float* lscale = (const float*)d_in[4];
    const float* cpb_w1 = (const float*)d_in[5];
    const float* cpb_b1 = (const float*)d_in[6];
    const float* cpb_w2 = (const float*)d_in[7];
    const float* proj_w = (const float*)d_in[8];
    const float* proj_b = (const float*)d_in[9];
    const float* n1g    = (const float*)d_in[10];
    const float* n1b    = (const float*)d_in[11];
    const float* mw1    = (const float*)d_in[12];
    const float* mb1    = (const float*)d_in[13];
    const float* mw2    = (const float*)d_in[14];
    const float* mb2    = (const float*)d_in[15];
    const float* n2g    = (const float*)d_in[16];
    const float* n2b    = (const float*)d_in[17];
    const float* pmg    = (const float*)d_in[18];
    const float* pmb    = (const float*)d_in[19];
    const float* pmw    = (const float*)d_in[20];
    float* out = (float*)d_out;

    // workspace (floats):
    //  xcur 12,845,056 | R1 38,535,168 | wbf 98,304 | out169 704 | rpb64 16,384
    float* wsf     = (float*)d_ws;
    float* xcur    = wsf;
    float* R1      = wsf + (size_t)12845056;
    short* qkvb    = (short*)R1;
    short* attnout = (short*)(R1 + (size_t)19267584);   // kTok*128 bf16
    float* raw1    = R1;
    short* hid     = (short*)R1;
    float* raw2    = R1 + (size_t)25690112;
    float* wtail   = R1 + (size_t)38535168;
    short* wqkvb   = (short*)wtail;          // 49,152 bf16
    short* wprojb  = wqkvb + 49152;          // 16,384
    short* wm1b    = wprojb + 16384;         // 65,536
    short* wm2b    = wm1b + 65536;           // 65,536
    float* out169  = wtail + 98304;
    float* rpb64   = out169 + 704;

    for (int i = 0; i < 2; ++i) {
        int shift = i ? 3 : 0;
        const float* xi = (i == 0) ? x_in : xcur;
        k_cpb<<<169, 256, 0, stream>>>(cpb_w1 + i * 1024, cpb_b1 + i * 512,
                                       cpb_w2 + i * 2048, out169);
        k_rpb<<<64, 256, 0, stream>>>(out169, rpb64);
        k_cvtw<<<24, 256, 0, stream>>>(qkv_w + i * 49152, wqkvb, 16, 384);
        k_cvtw<<<8, 256, 0, stream>>>(proj_w + i * 16384, wprojb, 16, 128);
        k_cvtw<<<32, 256, 0, stream>>>(mw1 + i * 65536, wm1b, 16, 512);
        k_cvtw<<<32, 256, 0, stream>>>(mw2 + i * 65536, wm2b, 64, 128);

        k_gemm<128, 1, false><<<dim3(6, 784), 256, 0, stream>>>(
            xi, wqkvb, q_bias + i * 128, v_bias + i * 128, qkvb, 384, shift);
        k_attn<<<2048, 256, 0, stream>>>(
            qkvb, rpb64, lscale + i * 4, attnout, shift);
        k_gemm<128, 0, true><<<dim3(2, 784), 256, 0, stream>>>(
            attnout, wprojb, nullptr, nullptr, raw1, 128, 0);
        k_resln<<<25088, 256, 0, stream>>>(
            raw1, proj_b + i * 128, n1g + i * 128, n1b + i * 128, xi, xcur, shift);
        k_gemm<128, 2, false><<<dim3(8, 784), 256, 0, stream>>>(
            xcur, wm1b, mb1 + i * 512, nullptr, hid, 512, 0);
        k_gemm<512, 0, true><<<dim3(2, 784), 256, 0, stream>>>(
            hid, wm2b, nullptr, nullptr, raw2, 128, 0);
        k_resln<<<25088, 256, 0, stream>>>(
            raw2, mb2 + i * 128, n2g + i * 128, n2b + i * 128, xcur, xcur, 0);
    }
    k_pm<<<784, 256, 0, stream>>>(xcur, pmg, pmb, pmw, out);
}

// Round 4
// 765.636 us; speedup vs baseline: 2.1442x; 1.1153x over previous
//
#include <hip/hip_runtime.h>
#include <math.h>

// ---------------------------------------------------------------------------
// SwinV2 stage: B=32, H=W=56, C=128, NH=4, hd=32, WS=7, N=49, DEPTH=2, shift=3
// Round 4: PatchMerging on MFMA (pmln + gemm); proj/mlp2 GEMMs fuse
// bias+LN+residual(+roll-back) in epilogue (k_resln and raw buffers deleted).
// ---------------------------------------------------------------------------

namespace {
constexpr int kTok = 32 * 56 * 56;   // 100352 tokens
}

typedef __attribute__((ext_vector_type(8))) short bf16x8;
typedef __attribute__((ext_vector_type(4))) float f32x4;

union FragU {
    int4 i4;
    bf16x8 b8;
    unsigned short u[8];
};

__device__ __forceinline__ short f2bf(float f) {
    unsigned u = __float_as_uint(f);
    return (short)((u + 0x7FFFu + ((u >> 16) & 1u)) >> 16);
}
__device__ __forceinline__ float bf2f(unsigned short u) {
    return __uint_as_float(((unsigned)u) << 16);
}
__device__ __forceinline__ float gelu_f(float x) {
    return 0.5f * x * (1.0f + erff(x * 0.70710678118654752f));
}

// --------------------------- CPB MLP (tiny) --------------------------------
__global__ __launch_bounds__(256) void k_cpb(
    const float* __restrict__ w1, const float* __restrict__ b1,
    const float* __restrict__ w2, float* __restrict__ out169) {
    int t = blockIdx.x;  // 0..168
    int ia = t / 13, ib = t % 13;
    float r0 = (float)(ia - 6) * (8.0f / 6.0f);
    float s0 = (r0 > 0.f) ? 1.f : (r0 < 0.f ? -1.f : 0.f);
    float t0 = s0 * log2f(fabsf(r0) + 1.0f) * (1.0f / 3.0f);
    float r1 = (float)(ib - 6) * (8.0f / 6.0f);
    float s1 = (r1 > 0.f) ? 1.f : (r1 < 0.f ? -1.f : 0.f);
    float t1 = s1 * log2f(fabsf(r1) + 1.0f) * (1.0f / 3.0f);

    int tid = threadIdx.x;
    float p0 = 0, p1 = 0, p2 = 0, p3 = 0;
    for (int c = tid; c < 512; c += 256) {
        float hv = fmaxf(t0 * w1[c] + t1 * w1[512 + c] + b1[c], 0.0f);
        p0 += hv * w2[c * 4 + 0];
        p1 += hv * w2[c * 4 + 1];
        p2 += hv * w2[c * 4 + 2];
        p3 += hv * w2[c * 4 + 3];
    }
    __shared__ float red[256][4];
    red[tid][0] = p0; red[tid][1] = p1; red[tid][2] = p2; red[tid][3] = p3;
    __syncthreads();
    for (int s = 128; s > 0; s >>= 1) {
        if (tid < s) {
            red[tid][0] += red[tid + s][0];
            red[tid][1] += red[tid + s][1];
            red[tid][2] += red[tid + s][2];
            red[tid][3] += red[tid + s][3];
        }
        __syncthreads();
    }
    if (tid < 4) out169[t * 4 + tid] = red[0][tid];
}

// rpb64[h][qrow64][krow64]; krow>=49 -> -30000 (k-pad baked in)
__global__ void k_rpb(const float* __restrict__ out169, float* __restrict__ rpb64) {
    int e = blockIdx.x * 256 + threadIdx.x;
    if (e >= 4 * 64 * 64) return;
    int h = e >> 12, r = e & 4095;
    int i = r >> 6, j = r & 63;
    float val;
    if (j >= 49) {
        val = -30000.0f;
    } else if (i >= 49) {
        val = 0.0f;
    } else {
        int dp = i / 7 - j / 7 + 6;
        int dq = i % 7 - j % 7 + 6;
        float v = out169[(dp * 13 + dq) * 4 + h];
        val = 16.0f / (1.0f + expf(-v));
    }
    rpb64[e] = val;
}

// ------------------- weight fp32 -> bf16 tiled image -----------------------
// slot slt = (nt*Kb + kb)*64 + nn holds W[kb*8+e][nt*64+nn], e=0..7.
__global__ __launch_bounds__(256) void k_cvtw(
    const float* __restrict__ W, short* __restrict__ Wb, int Kb, int N) {
    int slt = blockIdx.x * 256 + threadIdx.x;
    if (slt >= Kb * N) return;
    int nn = slt & 63;
    int tmp = slt >> 6;
    int kb = tmp % Kb;
    int nt = tmp / Kb;
    int n = nt * 64 + nn;
    int k0 = kb * 8;
    union { int4 i4; short s8[8]; } u;
#pragma unroll
    for (int e = 0; e < 8; ++e) u.s8[e] = f2bf(W[(size_t)(k0 + e) * N + n]);
    *(int4*)(Wb + (size_t)slt * 8) = u.i4;
}

// --------------------------- MFMA GEMM -------------------------------------
// C[M x N] = A[M x K] @ W[K x N] (+epilogue). BM=128, BN=64, 4 waves.
// EPI: 0 = raw fp32; 1 = qkv bias -> bf16 out (stride 384), roll on A;
//      2 = bias + gelu -> bf16 out (stride 512).
template <int K, int EPI, bool INBF16>
__global__ __launch_bounds__(256) void k_gemm(
    const void* __restrict__ Ain, const short* __restrict__ Wb,
    const float* __restrict__ bias0, const float* __restrict__ bias1,
    void* __restrict__ Out, int ostride, int shift) {
    constexpr int Kb = K / 8;
    constexpr int NC = K / 128;
    __shared__ int4 As4[2048];  // [16 kb][128 m], XOR-swizzled
    int tid = threadIdx.x;
    int nt = blockIdx.x, mt = blockIdx.y;
    int mb = mt * 128;
    int w = tid >> 6, l = tid & 63, lr = l & 15, lg = l >> 4;
    const f32x4 fz = {0.f, 0.f, 0.f, 0.f};
    f32x4 acc[2][4];
#pragma unroll
    for (int mi = 0; mi < 2; ++mi)
#pragma unroll
        for (int ni = 0; ni < 4; ++ni) acc[mi][ni] = fz;

    for (int c = 0; c < NC; ++c) {
        if (c) __syncthreads();
#pragma unroll
        for (int it = 0; it < 8; ++it) {
            int s = it * 256 + tid;
            int m = s >> 4, kb = s & 15;
            int gm = mb + m;
            if (EPI == 1) {
                if (shift) {
                    int b = gm / 3136, r = gm % 3136;
                    int hh = r / 56 + shift; if (hh >= 56) hh -= 56;
                    int ww = r % 56 + shift; if (ww >= 56) ww -= 56;
                    gm = b * 3136 + hh * 56 + ww;
                }
            }
            int slot = kb * 128 + ((m & ~7) | ((m ^ kb) & 7));
            if (INBF16) {
                As4[slot] = *(const int4*)((const short*)Ain + (size_t)gm * K + c * 128 + kb * 8);
            } else {
                const float* src = (const float*)Ain + (size_t)gm * K + c * 128 + kb * 8;
                float4 f0 = *(const float4*)src;
                float4 f1 = *(const float4*)(src + 4);
                union { int4 i4; short s8[8]; } u;
                u.s8[0] = f2bf(f0.x); u.s8[1] = f2bf(f0.y);
                u.s8[2] = f2bf(f0.z); u.s8[3] = f2bf(f0.w);
                u.s8[4] = f2bf(f1.x); u.s8[5] = f2bf(f1.y);
                u.s8[6] = f2bf(f1.z); u.s8[7] = f2bf(f1.w);
                As4[slot] = u.i4;
            }
        }
        __syncthreads();
        const short* wbase = Wb + ((size_t)nt * Kb + c * 16) * 64 * 8;
#pragma unroll
        for (int kk = 0; kk < 4; ++kk) {
            int kbl = kk * 4 + lg;
            int m0 = w * 32 + lr;
            bf16x8 a0 = *(const bf16x8*)&As4[kbl * 128 + ((m0 & ~7) | ((m0 ^ kbl) & 7))];
            int m1 = m0 + 16;
            bf16x8 a1 = *(const bf16x8*)&As4[kbl * 128 + ((m1 & ~7) | ((m1 ^ kbl) & 7))];
#pragma unroll
            for (int ni = 0; ni < 4; ++ni) {
                bf16x8 bfr = *(const bf16x8*)(wbase + ((size_t)(kbl * 64 + lr + 16 * ni)) * 8);
                acc[0][ni] = __builtin_amdgcn_mfma_f32_16x16x32_bf16(a0, bfr, acc[0][ni], 0, 0, 0);
                acc[1][ni] = __builtin_amdgcn_mfma_f32_16x16x32_bf16(a1, bfr, acc[1][ni], 0, 0, 0);
            }
        }
    }
#pragma unroll
    for (int ni = 0; ni < 4; ++ni) {
        int col = nt * 64 + ni * 16 + lr;
        float bv = 0.f;
        if (EPI == 1) bv = (col < 128) ? bias0[col] : ((col < 256) ? 0.f : bias1[col - 256]);
        if (EPI == 2) bv = bias0[col];
#pragma unroll
        for (int mi = 0; mi < 2; ++mi) {
#pragma unroll
            for (int r = 0; r < 4; ++r) {
                int row = mb + w * 32 + mi * 16 + lg * 4 + r;
                float v = acc[mi][ni][r] + bv;
                if (EPI == 0) {
                    ((float*)Out)[(size_t)row * ostride + col] = v;
                } else if (EPI == 1) {
                    ((short*)Out)[(size_t)row * 384 + col] = f2bf(v);
                } else {
                    ((short*)Out)[(size_t)row * 512 + col] = f2bf(gelu_f(v));
                }
            }
        }
    }
}

// ------------- MFMA GEMM + bias + LN + residual (+roll-back) ---------------
// N=128 (full row per block). xout[mo] = resid[mo] + LN(A[row] @ W + bias).
// BM=128, 4 waves, each wave 32 rows x 128 cols (acc[2][8]).
template <int K>
__global__ __launch_bounds__(256) void k_gemm_ln(
    const short* __restrict__ Ain, const short* __restrict__ Wb,
    const float* __restrict__ bias, const float* __restrict__ g,
    const float* __restrict__ bt, const float* __restrict__ resid,
    float* __restrict__ xout, int shift) {
    constexpr int Kb = K / 8;
    constexpr int NC = K / 128;
    __shared__ int4 As4[2048];
    int tid = threadIdx.x;
    int mb = blockIdx.x * 128;
    int w = tid >> 6, l = tid & 63, lr = l & 15, lg = l >> 4;
    const f32x4 fz = {0.f, 0.f, 0.f, 0.f};
    f32x4 acc[2][8];
#pragma unroll
    for (int mi = 0; mi < 2; ++mi)
#pragma unroll
        for (int ni = 0; ni < 8; ++ni) acc[mi][ni] = fz;

    for (int c = 0; c < NC; ++c) {
        if (c) __syncthreads();
#pragma unroll
        for (int it = 0; it < 8; ++it) {
            int s = it * 256 + tid;
            int m = s >> 4, kb = s & 15;
            int slot = kb * 128 + ((m & ~7) | ((m ^ kb) & 7));
            As4[slot] = *(const int4*)(Ain + (size_t)(mb + m) * K + c * 128 + kb * 8);
        }
        __syncthreads();
#pragma unroll
        for (int kk = 0; kk < 4; ++kk) {
            int kbl = kk * 4 + lg;
            int m0 = w * 32 + lr;
            bf16x8 a0 = *(const bf16x8*)&As4[kbl * 128 + ((m0 & ~7) | ((m0 ^ kbl) & 7))];
            int m1 = m0 + 16;
            bf16x8 a1 = *(const bf16x8*)&As4[kbl * 128 + ((m1 & ~7) | ((m1 ^ kbl) & 7))];
#pragma unroll
            for (int ni = 0; ni < 8; ++ni) {
                int ntw = ni >> 2;
                const short* wp = Wb + (((size_t)ntw * Kb + c * 16 + kbl) * 64 +
                                        (ni & 3) * 16 + lr) * 8;
                bf16x8 bfr = *(const bf16x8*)wp;
                acc[0][ni] = __builtin_amdgcn_mfma_f32_16x16x32_bf16(a0, bfr, acc[0][ni], 0, 0, 0);
                acc[1][ni] = __builtin_amdgcn_mfma_f32_16x16x32_bf16(a1, bfr, acc[1][ni], 0, 0, 0);
            }
        }
    }
    // epilogue: lane holds cols ni*16+lr for rows w*32+mi*16+lg*4+r
    float bv[8], gv[8], btv[8];
#pragma unroll
    for (int ni = 0; ni < 8; ++ni) {
        int col = ni * 16 + lr;
        bv[ni] = bias[col]; gv[ni] = g[col]; btv[ni] = bt[col];
    }
#pragma unroll
    for (int mi = 0; mi < 2; ++mi) {
#pragma unroll
        for (int r = 0; r < 4; ++r) {
            int row = mb + w * 32 + mi * 16 + lg * 4 + r;
            float v[8];
            float s1 = 0.f, s2 = 0.f;
#pragma unroll
            for (int ni = 0; ni < 8; ++ni) {
                v[ni] = acc[mi][ni][r] + bv[ni];
                s1 += v[ni];
                s2 = fmaf(v[ni], v[ni], s2);
            }
#pragma unroll
            for (int off = 8; off >= 1; off >>= 1) {   // reduce within 16-lane col group
                s1 += __shfl_xor(s1, off);
                s2 += __shfl_xor(s2, off);
            }
            float mean = s1 * (1.0f / 128.0f);
            float var = s2 * (1.0f / 128.0f) - mean * mean;
            float rstd = rsqrtf(var + 1e-5f);
            int mo = row;
            if (shift) {
                int b = row / 3136, rr = row % 3136;
                int hh = rr / 56 + shift; if (hh >= 56) hh -= 56;
                int ww = rr % 56 + shift; if (ww >= 56) ww -= 56;
                mo = b * 3136 + hh * 56 + ww;
            }
            size_t base = (size_t)mo * 128;
#pragma unroll
            for (int ni = 0; ni < 8; ++ni) {
                int col = ni * 16 + lr;
                float o = resid[base + col] + (v[ni] - mean) * rstd * gv[ni] + btv[ni];
                xout[base + col] = o;
            }
        }
    }
}

// --------------------------- MFMA windowed attention -----------------------
// grid 2048 (one block per window), 4 waves = 4 heads. qkv bf16 in,
// attnout bf16 out. S^T = mfma(K,Q): lane owns one q-row per col-tile.
__global__ __launch_bounds__(256) void k_attn(
    const short* __restrict__ qkv, const float* __restrict__ rpb64,
    const float* __restrict__ ls, short* __restrict__ aout, int shift) {
    // per wave: P [64][72] bf16 (4608) + Vt [32][72] bf16 (2304)
    __shared__ short lds[4 * 6912];
    int wid = blockIdx.x;
    int b = wid >> 6, wrem = wid & 63;
    int wh = wrem >> 3, ww_ = wrem & 7;
    int h = threadIdx.x >> 6;
    int l = threadIdx.x & 63, lr = l & 15, lg = l >> 4;
    short* Pl = lds + h * 6912;
    short* Vt = Pl + 4608;
    int tokbase = b * 3136 + wh * 7 * 56 + ww_ * 7;

    // ---- load Q,K fragments direct from global; normalize in-register ----
    float scale = __expf(fminf(ls[h], 4.6051702f));  // ln(100)
    int4 qf[4], kf[4];
    const int4 zero4 = make_int4(0, 0, 0, 0);
#pragma unroll
    for (int t = 0; t < 4; ++t) {
        int i = t * 16 + lr;
        bool valid = (i < 49);
        int tok = tokbase + (i / 7) * 56 + (i % 7);
        const short* base = qkv + (size_t)tok * 384 + h * 32 + lg * 8;
        qf[t] = valid ? *(const int4*)base : zero4;
        kf[t] = valid ? *(const int4*)(base + 128) : zero4;
    }
#pragma unroll
    for (int t = 0; t < 4; ++t) {
#pragma unroll
        for (int m = 0; m < 2; ++m) {   // m=0: q, m=1: k
            FragU u; u.i4 = m ? kf[t] : qf[t];
            float x[8], ss = 0.f;
#pragma unroll
            for (int e = 0; e < 8; ++e) { x[e] = bf2f(u.u[e]); ss = fmaf(x[e], x[e], ss); }
            ss += __shfl_xor(ss, 16);
            ss += __shfl_xor(ss, 32);
            float inv = 1.0f / fmaxf(sqrtf(ss), 1e-12f);
            if (m == 0) inv *= scale;
#pragma unroll
            for (int e = 0; e < 8; ++e) u.u[e] = (unsigned short)f2bf(x[e] * inv);
            if (m) kf[t] = u.i4; else qf[t] = u.i4;
        }
    }

    // ---- stage V transposed into LDS (Vt[d][j], stride 72) ----
    for (int t = l; t < 480; t += 64) {
        Vt[(t / 15) * 72 + 49 + (t % 15)] = 0;
    }
    for (int t = l; t < 196; t += 64) {
        int j = t >> 2, dq = t & 3;
        int tok = tokbase + (j / 7) * 56 + (j % 7);
        FragU u;
        u.i4 = *(const int4*)(qkv + (size_t)tok * 384 + 256 + h * 32 + dq * 8);
#pragma unroll
        for (int e = 0; e < 8; ++e) Vt[(dq * 8 + e) * 72 + j] = (short)u.u[e];
    }

    // ---- S^T = Kn @ Qn^T ----
    const f32x4 fz = {0.f, 0.f, 0.f, 0.f};
    f32x4 acc[4][4];
#pragma unroll
    for (int qt = 0; qt < 4; ++qt)
#pragma unroll
        for (int jt = 0; jt < 4; ++jt) acc[qt][jt] = fz;
#pragma unroll
    for (int jt = 0; jt < 4; ++jt) {
        FragU a; a.i4 = kf[jt];
#pragma unroll
        for (int qt = 0; qt < 4; ++qt) {
            FragU bq; bq.i4 = qf[qt];
            acc[qt][jt] = __builtin_amdgcn_mfma_f32_16x16x32_bf16(a.b8, bq.b8, acc[qt][jt], 0, 0, 0);
        }
    }

    // ---- + rpb (k-pad baked) + shift mask; softmax per q-row; pack P ----
    bool edge = (shift != 0) && ((wh == 7) || (ww_ == 7));
    const float* rbase = rpb64 + h * 4096;
#pragma unroll
    for (int qt = 0; qt < 4; ++qt) {
        int qi = qt * 16 + lr;
        int qc = (qi < 49) ? qi : 48;
        int rlq = 0, clq = 0;
        if (edge) {
            rlq = (wh == 7) ? ((qc / 7) < 4 ? 1 : 2) : 0;
            clq = (ww_ == 7) ? ((qc % 7) < 4 ? 1 : 2) : 0;
        }
#pragma unroll
        for (int jt = 0; jt < 4; ++jt) {
            float4 rv = *(const float4*)(rbase + qc * 64 + jt * 16 + lg * 4);
            float rr[4] = {rv.x, rv.y, rv.z, rv.w};
#pragma unroll
            for (int r = 0; r < 4; ++r) {
                float v = acc[qt][jt][r] + rr[r];
                if (edge) {
                    int j = jt * 16 + lg * 4 + r;
                    int jc = (j < 49) ? j : 48;
                    int rlk = (wh == 7) ? ((jc / 7) < 4 ? 1 : 2) : 0;
                    int clk = (ww_ == 7) ? ((jc % 7) < 4 ? 1 : 2) : 0;
                    if (rlk != rlq || clk != clq) v -= 100.0f;
                }
                acc[qt][jt][r] = v;
            }
        }
        float m = -1e30f;
#pragma unroll
        for (int jt = 0; jt < 4; ++jt)
#pragma unroll
            for (int r = 0; r < 4; ++r) m = fmaxf(m, acc[qt][jt][r]);
        m = fmaxf(m, __shfl_xor(m, 16));
        m = fmaxf(m, __shfl_xor(m, 32));
        float s = 0.f;
#pragma unroll
        for (int jt = 0; jt < 4; ++jt)
#pragma unroll
            for (int r = 0; r < 4; ++r) {
                float p = __expf(acc[qt][jt][r] - m);
                acc[qt][jt][r] = p;
                s += p;
            }
        s += __shfl_xor(s, 16);
        s += __shfl_xor(s, 32);
        float inv = 1.0f / s;
        int prow = (qt * 16 + lr) * 72;
#pragma unroll
        for (int jt = 0; jt < 4; ++jt) {
            unsigned lo = (unsigned)(unsigned short)f2bf(acc[qt][jt][0] * inv) |
                          ((unsigned)(unsigned short)f2bf(acc[qt][jt][1] * inv) << 16);
            unsigned hi = (unsigned)(unsigned short)f2bf(acc[qt][jt][2] * inv) |
                          ((unsigned)(unsigned short)f2bf(acc[qt][jt][3] * inv) << 16);
            *(int2*)&Pl[prow + jt * 16 + lg * 4] = make_int2((int)lo, (int)hi);
        }
    }

    // ---- out^T = V^T @ P^T ----
    f32x4 oacc[2][4];
#pragma unroll
    for (int mi = 0; mi < 2; ++mi)
#pragma unroll
        for (int ni = 0; ni < 4; ++ni) oacc[mi][ni] = fz;
#pragma unroll
    for (int kc = 0; kc < 2; ++kc) {
        FragU va[2], pb[4];
#pragma unroll
        for (int mi = 0; mi < 2; ++mi)
            va[mi].i4 = *(const int4*)&Vt[(mi * 16 + lr) * 72 + kc * 32 + lg * 8];
#pragma unroll
        for (int ni = 0; ni < 4; ++ni)
            pb[ni].i4 = *(const int4*)&Pl[(ni * 16 + lr) * 72 + kc * 32 + lg * 8];
#pragma unroll
        for (int mi = 0; mi < 2; ++mi)
#pragma unroll
            for (int ni = 0; ni < 4; ++ni)
                oacc[mi][ni] = __builtin_amdgcn_mfma_f32_16x16x32_bf16(
                    va[mi].b8, pb[ni].b8, oacc[mi][ni], 0, 0, 0);
    }

#pragma unroll
    for (int ni = 0; ni < 4; ++ni) {
        int qrow = ni * 16 + lr;
        if (qrow < 49) {
            int tok = tokbase + (qrow / 7) * 56 + (qrow % 7);
#pragma unroll
            for (int mi = 0; mi < 2; ++mi) {
                unsigned lo = (unsigned)(unsigned short)f2bf(oacc[mi][ni][0]) |
                              ((unsigned)(unsigned short)f2bf(oacc[mi][ni][1]) << 16);
                unsigned hi = (unsigned)(unsigned short)f2bf(oacc[mi][ni][2]) |
                              ((unsigned)(unsigned short)f2bf(oacc[mi][ni][3]) << 16);
                *(int2*)&aout[(size_t)tok * 128 + h * 32 + mi * 16 + lg * 4] =
                    make_int2((int)lo, (int)hi);
            }
        }
    }
}

// ------------- PatchMerging gather + LN -> bf16 rows [25088][512] ----------
// one wave per output token; lane handles 8 cols.
__global__ __launch_bounds__(256) void k_pmln(
    const float* __restrict__ x, const float* __restrict__ g,
    const float* __restrict__ bt, short* __restrict__ outb) {
    int m2 = blockIdx.x * 4 + (threadIdx.x >> 6);
    int l = threadIdx.x & 63;
    int b = m2 / 784, r = m2 % 784;
    int h2 = r / 28, w2 = r % 28;
    int q0 = l * 8;
    int i2 = q0 >> 8, j2 = (q0 >> 7) & 1, c = q0 & 127;
    const float* src = x + (size_t)((b * 56 + 2 * h2 + i2) * 56 + 2 * w2 + j2) * 128 + c;
    float4 f0 = *(const float4*)src;
    float4 f1 = *(const float4*)(src + 4);
    float v[8] = {f0.x, f0.y, f0.z, f0.w, f1.x, f1.y, f1.z, f1.w};
    float s1 = 0.f, s2 = 0.f;
#pragma unroll
    for (int e = 0; e < 8; ++e) { s1 += v[e]; s2 = fmaf(v[e], v[e], s2); }
#pragma unroll
    for (int off = 32; off >= 1; off >>= 1) {
        s1 += __shfl_xor(s1, off);
        s2 += __shfl_xor(s2, off);
    }
    float mean = s1 * (1.0f / 512.0f);
    float var = s2 * (1.0f / 512.0f) - mean * mean;
    float rstd = rsqrtf(var + 1e-5f);
    union { int4 i4; short s8[8]; } u;
#pragma unroll
    for (int e = 0; e < 8; ++e)
        u.s8[e] = f2bf((v[e] - mean) * rstd * g[q0 + e] + bt[q0 + e]);
    *(int4*)(outb + (size_t)m2 * 512 + q0) = u.i4;
}

// ---------------------------------------------------------------------------
extern "C" void kernel_launch(void* const* d_in, const int* in_sizes, int n_in,
                              void* d_out, int out_size, void* d_ws, size_t ws_size,
                              hipStream_t stream) {
    const float* x_in   = (const float*)d_in[0];
    const float* qkv_w  = (const float*)d_in[1];
    const float* q_bias = (const float*)d_in[2];
    const float* v_bias = (const float*)d_in[3];
    const float* lscale = (const float*)d_in[4];
    const float* cpb_w1 = (const float*)d_in[5];
    const float* cpb_b1 = (const float*)d_in[6];
    const float* cpb_w2 = (const float*)d_in[7];
    const float* proj_w = (const float*)d_in[8];
    const float* proj_b = (const float*)d_in[9];
    const float* n1g    = (const float*)d_in[10];
    const float* n1b    = (const float*)d_in[11];
    const float* mw1    = (const float*)d_in[12];
    const float* mb1    = (const float*)d_in[13];
    const float* mw2    = (const float*)d_in[14];
    const float* mb2    = (const float*)d_in[15];
    const float* n2g    = (const float*)d_in[16];
    const float* n2b    = (const float*)d_in[17];
    const float* pmg    = (const float*)d_in[18];
    const float* pmb    = (const float*)d_in[19];
    const float* pmw    = (const float*)d_in[20];
    float* out = (float*)d_out;

    // workspace (floats):
    //  xcur 12,845,056 | R1 38,535,168 | wtail 163,840 | out169 704 | rpb64 16,384
    //  R1 overlays: qkvb bf16 [0,19.27M) ; attnout bf16 [19.27M,25.69M) ;
    //  hid bf16 [0,25.69M) ; pm bf16-in [0,6.43M)
    float* wsf     = (float*)d_ws;
    float* xcur    = wsf;
    float* R1      = wsf + (size_t)12845056;
    short* qkvb    = (short*)R1;
    short* attnout = (short*)(R1 + (size_t)19267584);   // kTok*128 bf16
    short* hid     = (short*)R1;
    short* pmin    = (short*)R1;                        // 25088*512 bf16
    float* wtail   = R1 + (size_t)38535168;
    short* wqkvb   = (short*)wtail;          // 49,152 bf16
    short* wprojb  = wqkvb + 49152;          // 16,384
    short* wm1b    = wprojb + 16384;         // 65,536
    short* wm2b    = wm1b + 65536;           // 65,536
    short* wpmb    = wm2b + 65536;           // 131,072
    float* out169  = wtail + 163840;
    float* rpb64   = out169 + 704;

    for (int i = 0; i < 2; ++i) {
        int shift = i ? 3 : 0;
        const float* xi = (i == 0) ? x_in : xcur;
        k_cpb<<<169, 256, 0, stream>>>(cpb_w1 + i * 1024, cpb_b1 + i * 512,
                                       cpb_w2 + i * 2048, out169);
        k_rpb<<<64, 256, 0, stream>>>(out169, rpb64);
        k_cvtw<<<24, 256, 0, stream>>>(qkv_w + i * 49152, wqkvb, 16, 384);
        k_cvtw<<<8, 256, 0, stream>>>(proj_w + i * 16384, wprojb, 16, 128);
        k_cvtw<<<32, 256, 0, stream>>>(mw1 + i * 65536, wm1b, 16, 512);
        k_cvtw<<<32, 256, 0, stream>>>(mw2 + i * 65536, wm2b, 64, 128);

        k_gemm<128, 1, false><<<dim3(6, 784), 256, 0, stream>>>(
            xi, wqkvb, q_bias + i * 128, v_bias + i * 128, qkvb, 384, shift);
        k_attn<<<2048, 256, 0, stream>>>(
            qkvb, rpb64, lscale + i * 4, attnout, shift);
        k_gemm_ln<128><<<784, 256, 0, stream>>>(
            attnout, wprojb, proj_b + i * 128, n1g + i * 128, n1b + i * 128,
            xi, xcur, shift);
        k_gemm<128, 2, false><<<dim3(8, 784), 256, 0, stream>>>(
            xcur, wm1b, mb1 + i * 512, nullptr, hid, 512, 0);
        k_gemm_ln<512><<<784, 256, 0, stream>>>(
            hid, wm2b, mb2 + i * 128, n2g + i * 128, n2b + i * 128,
            xcur, xcur, 0);
    }
    k_cvtw<<<64, 256, 0, stream>>>(pmw, wpmb, 64, 256);
    k_pmln<<<6272, 256, 0, stream>>>(xcur, pmg, pmb, pmin);
    k_gemm<512, 0, true><<<dim3(4, 196), 256, 0, stream>>>(
        pmin, wpmb, nullptr, nullptr, out, 256, 0);
}

// Round 5
// 621.608 us; speedup vs baseline: 2.6411x; 1.2317x over previous
//
#include <hip/hip_runtime.h>
#include <math.h>

// ---------------------------------------------------------------------------
// SwinV2 stage: B=32, H=W=56, C=128, NH=4, hd=32, WS=7, N=49, DEPTH=2, shift=3
// Round 5: XCD-chunked 1D grid for GEMMs (kills cross-XCD A refetch);
// persistent bf16 activation image xb (all GEMM A-operands bf16).
// ---------------------------------------------------------------------------

namespace {
constexpr int kTok = 32 * 56 * 56;   // 100352 tokens
}

typedef __attribute__((ext_vector_type(8))) short bf16x8;
typedef __attribute__((ext_vector_type(4))) float f32x4;

union FragU {
    int4 i4;
    bf16x8 b8;
    unsigned short u[8];
};

__device__ __forceinline__ short f2bf(float f) {
    unsigned u = __float_as_uint(f);
    return (short)((u + 0x7FFFu + ((u >> 16) & 1u)) >> 16);
}
__device__ __forceinline__ float bf2f(unsigned short u) {
    return __uint_as_float(((unsigned)u) << 16);
}
__device__ __forceinline__ float gelu_f(float x) {
    return 0.5f * x * (1.0f + erff(x * 0.70710678118654752f));
}

// --------------------------- CPB MLP (tiny) --------------------------------
__global__ __launch_bounds__(256) void k_cpb(
    const float* __restrict__ w1, const float* __restrict__ b1,
    const float* __restrict__ w2, float* __restrict__ out169) {
    int t = blockIdx.x;  // 0..168
    int ia = t / 13, ib = t % 13;
    float r0 = (float)(ia - 6) * (8.0f / 6.0f);
    float s0 = (r0 > 0.f) ? 1.f : (r0 < 0.f ? -1.f : 0.f);
    float t0 = s0 * log2f(fabsf(r0) + 1.0f) * (1.0f / 3.0f);
    float r1 = (float)(ib - 6) * (8.0f / 6.0f);
    float s1 = (r1 > 0.f) ? 1.f : (r1 < 0.f ? -1.f : 0.f);
    float t1 = s1 * log2f(fabsf(r1) + 1.0f) * (1.0f / 3.0f);

    int tid = threadIdx.x;
    float p0 = 0, p1 = 0, p2 = 0, p3 = 0;
    for (int c = tid; c < 512; c += 256) {
        float hv = fmaxf(t0 * w1[c] + t1 * w1[512 + c] + b1[c], 0.0f);
        p0 += hv * w2[c * 4 + 0];
        p1 += hv * w2[c * 4 + 1];
        p2 += hv * w2[c * 4 + 2];
        p3 += hv * w2[c * 4 + 3];
    }
    __shared__ float red[256][4];
    red[tid][0] = p0; red[tid][1] = p1; red[tid][2] = p2; red[tid][3] = p3;
    __syncthreads();
    for (int s = 128; s > 0; s >>= 1) {
        if (tid < s) {
            red[tid][0] += red[tid + s][0];
            red[tid][1] += red[tid + s][1];
            red[tid][2] += red[tid + s][2];
            red[tid][3] += red[tid + s][3];
        }
        __syncthreads();
    }
    if (tid < 4) out169[t * 4 + tid] = red[0][tid];
}

// rpb64[h][qrow64][krow64]; krow>=49 -> -30000 (k-pad baked in)
__global__ void k_rpb(const float* __restrict__ out169, float* __restrict__ rpb64) {
    int e = blockIdx.x * 256 + threadIdx.x;
    if (e >= 4 * 64 * 64) return;
    int h = e >> 12, r = e & 4095;
    int i = r >> 6, j = r & 63;
    float val;
    if (j >= 49) {
        val = -30000.0f;
    } else if (i >= 49) {
        val = 0.0f;
    } else {
        int dp = i / 7 - j / 7 + 6;
        int dq = i % 7 - j % 7 + 6;
        float v = out169[(dp * 13 + dq) * 4 + h];
        val = 16.0f / (1.0f + expf(-v));
    }
    rpb64[e] = val;
}

// ------------------- weight fp32 -> bf16 tiled image -----------------------
// slot slt = (nt*Kb + kb)*64 + nn holds W[kb*8+e][nt*64+nn], e=0..7.
__global__ __launch_bounds__(256) void k_cvtw(
    const float* __restrict__ W, short* __restrict__ Wb, int Kb, int N) {
    int slt = blockIdx.x * 256 + threadIdx.x;
    if (slt >= Kb * N) return;
    int nn = slt & 63;
    int tmp = slt >> 6;
    int kb = tmp % Kb;
    int nt = tmp / Kb;
    int n = nt * 64 + nn;
    int k0 = kb * 8;
    union { int4 i4; short s8[8]; } u;
#pragma unroll
    for (int e = 0; e < 8; ++e) u.s8[e] = f2bf(W[(size_t)(k0 + e) * N + n]);
    *(int4*)(Wb + (size_t)slt * 8) = u.i4;
}

// ------------------- activation fp32 -> bf16 rows --------------------------
__global__ __launch_bounds__(256) void k_cvtx(
    const float* __restrict__ x, short* __restrict__ xb) {
    size_t e = ((size_t)blockIdx.x * 256 + threadIdx.x) * 8;
    const float* src = x + e;
    float4 f0 = *(const float4*)src;
    float4 f1 = *(const float4*)(src + 4);
    union { int4 i4; short s8[8]; } u;
    u.s8[0] = f2bf(f0.x); u.s8[1] = f2bf(f0.y);
    u.s8[2] = f2bf(f0.z); u.s8[3] = f2bf(f0.w);
    u.s8[4] = f2bf(f1.x); u.s8[5] = f2bf(f1.y);
    u.s8[6] = f2bf(f1.z); u.s8[7] = f2bf(f1.w);
    *(int4*)(xb + e) = u.i4;
}

// --------------------------- MFMA GEMM (bf16 A) ----------------------------
// C[M x N] = A[M x K] @ W[K x N] (+epilogue). BM=128, BN=64, 4 waves.
// 1D grid of NT*MT blocks, XCD-chunked: xcd = bid&7 owns contiguous mt range,
// iterating nt fastest -> A-tile reuse stays inside one XCD's L2.
// EPI: 0 = raw fp32; 1 = qkv bias -> bf16 out (stride 384), roll on A;
//      2 = bias + gelu -> bf16 out (stride 512).
template <int K, int EPI, int NT>
__global__ __launch_bounds__(256) void k_gemm(
    const short* __restrict__ Ain, const short* __restrict__ Wb,
    const float* __restrict__ bias0, const float* __restrict__ bias1,
    void* __restrict__ Out, int ostride, int shift) {
    constexpr int Kb = K / 8;
    constexpr int NC = K / 128;
    __shared__ int4 As4[2048];  // [16 kb][128 m], XOR-swizzled
    int tid = threadIdx.x;
    int nwg = gridDim.x;
    int chunk = nwg >> 3;
    int lid = (blockIdx.x & 7) * chunk + (blockIdx.x >> 3);
    int mt = lid / NT, nt = lid - mt * NT;
    int mb = mt * 128;
    int w = tid >> 6, l = tid & 63, lr = l & 15, lg = l >> 4;
    const f32x4 fz = {0.f, 0.f, 0.f, 0.f};
    f32x4 acc[2][4];
#pragma unroll
    for (int mi = 0; mi < 2; ++mi)
#pragma unroll
        for (int ni = 0; ni < 4; ++ni) acc[mi][ni] = fz;

    for (int c = 0; c < NC; ++c) {
        if (c) __syncthreads();
#pragma unroll
        for (int it = 0; it < 8; ++it) {
            int s = it * 256 + tid;
            int m = s >> 4, kb = s & 15;
            int gm = mb + m;
            if (EPI == 1 && shift) {
                int b = gm / 3136, r = gm % 3136;
                int hh = r / 56 + shift; if (hh >= 56) hh -= 56;
                int ww = r % 56 + shift; if (ww >= 56) ww -= 56;
                gm = b * 3136 + hh * 56 + ww;
            }
            int slot = kb * 128 + ((m & ~7) | ((m ^ kb) & 7));
            As4[slot] = *(const int4*)(Ain + (size_t)gm * K + c * 128 + kb * 8);
        }
        __syncthreads();
        const short* wbase = Wb + ((size_t)nt * Kb + c * 16) * 64 * 8;
#pragma unroll
        for (int kk = 0; kk < 4; ++kk) {
            int kbl = kk * 4 + lg;
            int m0 = w * 32 + lr;
            bf16x8 a0 = *(const bf16x8*)&As4[kbl * 128 + ((m0 & ~7) | ((m0 ^ kbl) & 7))];
            int m1 = m0 + 16;
            bf16x8 a1 = *(const bf16x8*)&As4[kbl * 128 + ((m1 & ~7) | ((m1 ^ kbl) & 7))];
#pragma unroll
            for (int ni = 0; ni < 4; ++ni) {
                bf16x8 bfr = *(const bf16x8*)(wbase + ((size_t)(kbl * 64 + lr + 16 * ni)) * 8);
                acc[0][ni] = __builtin_amdgcn_mfma_f32_16x16x32_bf16(a0, bfr, acc[0][ni], 0, 0, 0);
                acc[1][ni] = __builtin_amdgcn_mfma_f32_16x16x32_bf16(a1, bfr, acc[1][ni], 0, 0, 0);
            }
        }
    }
#pragma unroll
    for (int ni = 0; ni < 4; ++ni) {
        int col = nt * 64 + ni * 16 + lr;
        float bv = 0.f;
        if (EPI == 1) bv = (col < 128) ? bias0[col] : ((col < 256) ? 0.f : bias1[col - 256]);
        if (EPI == 2) bv = bias0[col];
#pragma unroll
        for (int mi = 0; mi < 2; ++mi) {
#pragma unroll
            for (int r = 0; r < 4; ++r) {
                int row = mb + w * 32 + mi * 16 + lg * 4 + r;
                float v = acc[mi][ni][r] + bv;
                if (EPI == 0) {
                    ((float*)Out)[(size_t)row * ostride + col] = v;
                } else if (EPI == 1) {
                    ((short*)Out)[(size_t)row * 384 + col] = f2bf(v);
                } else {
                    ((short*)Out)[(size_t)row * 512 + col] = f2bf(gelu_f(v));
                }
            }
        }
    }
}

// ------------- MFMA GEMM + bias + LN + residual (+roll-back) ---------------
// N=128 (full row per block). xout[mo] = resid[mo] + LN(A[row] @ W + bias).
// Also writes bf16 copy xoutb (GEMM A-image for the next layer).
template <int K>
__global__ __launch_bounds__(256) void k_gemm_ln(
    const short* __restrict__ Ain, const short* __restrict__ Wb,
    const float* __restrict__ bias, const float* __restrict__ g,
    const float* __restrict__ bt, const float* __restrict__ resid,
    float* __restrict__ xout, short* __restrict__ xoutb, int shift) {
    constexpr int Kb = K / 8;
    constexpr int NC = K / 128;
    __shared__ int4 As4[2048];
    int tid = threadIdx.x;
    int mb = blockIdx.x * 128;
    int w = tid >> 6, l = tid & 63, lr = l & 15, lg = l >> 4;
    const f32x4 fz = {0.f, 0.f, 0.f, 0.f};
    f32x4 acc[2][8];
#pragma unroll
    for (int mi = 0; mi < 2; ++mi)
#pragma unroll
        for (int ni = 0; ni < 8; ++ni) acc[mi][ni] = fz;

    for (int c = 0; c < NC; ++c) {
        if (c) __syncthreads();
#pragma unroll
        for (int it = 0; it < 8; ++it) {
            int s = it * 256 + tid;
            int m = s >> 4, kb = s & 15;
            int slot = kb * 128 + ((m & ~7) | ((m ^ kb) & 7));
            As4[slot] = *(const int4*)(Ain + (size_t)(mb + m) * K + c * 128 + kb * 8);
        }
        __syncthreads();
#pragma unroll
        for (int kk = 0; kk < 4; ++kk) {
            int kbl = kk * 4 + lg;
            int m0 = w * 32 + lr;
            bf16x8 a0 = *(const bf16x8*)&As4[kbl * 128 + ((m0 & ~7) | ((m0 ^ kbl) & 7))];
            int m1 = m0 + 16;
            bf16x8 a1 = *(const bf16x8*)&As4[kbl * 128 + ((m1 & ~7) | ((m1 ^ kbl) & 7))];
#pragma unroll
            for (int ni = 0; ni < 8; ++ni) {
                int ntw = ni >> 2;
                const short* wp = Wb + (((size_t)ntw * Kb + c * 16 + kbl) * 64 +
                                        (ni & 3) * 16 + lr) * 8;
                bf16x8 bfr = *(const bf16x8*)wp;
                acc[0][ni] = __builtin_amdgcn_mfma_f32_16x16x32_bf16(a0, bfr, acc[0][ni], 0, 0, 0);
                acc[1][ni] = __builtin_amdgcn_mfma_f32_16x16x32_bf16(a1, bfr, acc[1][ni], 0, 0, 0);
            }
        }
    }
    float bv[8], gv[8], btv[8];
#pragma unroll
    for (int ni = 0; ni < 8; ++ni) {
        int col = ni * 16 + lr;
        bv[ni] = bias[col]; gv[ni] = g[col]; btv[ni] = bt[col];
    }
#pragma unroll
    for (int mi = 0; mi < 2; ++mi) {
#pragma unroll
        for (int r = 0; r < 4; ++r) {
            int row = mb + w * 32 + mi * 16 + lg * 4 + r;
            float v[8];
            float s1 = 0.f, s2 = 0.f;
#pragma unroll
            for (int ni = 0; ni < 8; ++ni) {
                v[ni] = acc[mi][ni][r] + bv[ni];
                s1 += v[ni];
                s2 = fmaf(v[ni], v[ni], s2);
            }
#pragma unroll
            for (int off = 8; off >= 1; off >>= 1) {
                s1 += __shfl_xor(s1, off);
                s2 += __shfl_xor(s2, off);
            }
            float mean = s1 * (1.0f / 128.0f);
            float var = s2 * (1.0f / 128.0f) - mean * mean;
            float rstd = rsqrtf(var + 1e-5f);
            int mo = row;
            if (shift) {
                int b = row / 3136, rr = row % 3136;
                int hh = rr / 56 + shift; if (hh >= 56) hh -= 56;
                int ww = rr % 56 + shift; if (ww >= 56) ww -= 56;
                mo = b * 3136 + hh * 56 + ww;
            }
            size_t base = (size_t)mo * 128;
#pragma unroll
            for (int ni = 0; ni < 8; ++ni) {
                int col = ni * 16 + lr;
                float o = resid[base + col] + (v[ni] - mean) * rstd * gv[ni] + btv[ni];
                xout[base + col] = o;
                xoutb[base + col] = f2bf(o);
            }
        }
    }
}

// --------------------------- MFMA windowed attention -----------------------
__global__ __launch_bounds__(256) void k_attn(
    const short* __restrict__ qkv, const float* __restrict__ rpb64,
    const float* __restrict__ ls, short* __restrict__ aout, int shift) {
    __shared__ short lds[4 * 6912];
    int wid = blockIdx.x;
    int b = wid >> 6, wrem = wid & 63;
    int wh = wrem >> 3, ww_ = wrem & 7;
    int h = threadIdx.x >> 6;
    int l = threadIdx.x & 63, lr = l & 15, lg = l >> 4;
    short* Pl = lds + h * 6912;
    short* Vt = Pl + 4608;
    int tokbase = b * 3136 + wh * 7 * 56 + ww_ * 7;

    float scale = __expf(fminf(ls[h], 4.6051702f));  // ln(100)
    int4 qf[4], kf[4];
    const int4 zero4 = make_int4(0, 0, 0, 0);
#pragma unroll
    for (int t = 0; t < 4; ++t) {
        int i = t * 16 + lr;
        bool valid = (i < 49);
        int tok = tokbase + (i / 7) * 56 + (i % 7);
        const short* base = qkv + (size_t)tok * 384 + h * 32 + lg * 8;
        qf[t] = valid ? *(const int4*)base : zero4;
        kf[t] = valid ? *(const int4*)(base + 128) : zero4;
    }
#pragma unroll
    for (int t = 0; t < 4; ++t) {
#pragma unroll
        for (int m = 0; m < 2; ++m) {
            FragU u; u.i4 = m ? kf[t] : qf[t];
            float x[8], ss = 0.f;
#pragma unroll
            for (int e = 0; e < 8; ++e) { x[e] = bf2f(u.u[e]); ss = fmaf(x[e], x[e], ss); }
            ss += __shfl_xor(ss, 16);
            ss += __shfl_xor(ss, 32);
            float inv = 1.0f / fmaxf(sqrtf(ss), 1e-12f);
            if (m == 0) inv *= scale;
#pragma unroll
            for (int e = 0; e < 8; ++e) u.u[e] = (unsigned short)f2bf(x[e] * inv);
            if (m) kf[t] = u.i4; else qf[t] = u.i4;
        }
    }

    for (int t = l; t < 480; t += 64) {
        Vt[(t / 15) * 72 + 49 + (t % 15)] = 0;
    }
    for (int t = l; t < 196; t += 64) {
        int j = t >> 2, dq = t & 3;
        int tok = tokbase + (j / 7) * 56 + (j % 7);
        FragU u;
        u.i4 = *(const int4*)(qkv + (size_t)tok * 384 + 256 + h * 32 + dq * 8);
#pragma unroll
        for (int e = 0; e < 8; ++e) Vt[(dq * 8 + e) * 72 + j] = (short)u.u[e];
    }

    const f32x4 fz = {0.f, 0.f, 0.f, 0.f};
    f32x4 acc[4][4];
#pragma unroll
    for (int qt = 0; qt < 4; ++qt)
#pragma unroll
        for (int jt = 0; jt < 4; ++jt) acc[qt][jt] = fz;
#pragma unroll
    for (int jt = 0; jt < 4; ++jt) {
        FragU a; a.i4 = kf[jt];
#pragma unroll
        for (int qt = 0; qt < 4; ++qt) {
            FragU bq; bq.i4 = qf[qt];
            acc[qt][jt] = __builtin_amdgcn_mfma_f32_16x16x32_bf16(a.b8, bq.b8, acc[qt][jt], 0, 0, 0);
        }
    }

    bool edge = (shift != 0) && ((wh == 7) || (ww_ == 7));
    const float* rbase = rpb64 + h * 4096;
#pragma unroll
    for (int qt = 0; qt < 4; ++qt) {
        int qi = qt * 16 + lr;
        int qc = (qi < 49) ? qi : 48;
        int rlq = 0, clq = 0;
        if (edge) {
            rlq = (wh == 7) ? ((qc / 7) < 4 ? 1 : 2) : 0;
            clq = (ww_ == 7) ? ((qc % 7) < 4 ? 1 : 2) : 0;
        }
#pragma unroll
        for (int jt = 0; jt < 4; ++jt) {
            float4 rv = *(const float4*)(rbase + qc * 64 + jt * 16 + lg * 4);
            float rr[4] = {rv.x, rv.y, rv.z, rv.w};
#pragma unroll
            for (int r = 0; r < 4; ++r) {
                float v = acc[qt][jt][r] + rr[r];
                if (edge) {
                    int j = jt * 16 + lg * 4 + r;
                    int jc = (j < 49) ? j : 48;
                    int rlk = (wh == 7) ? ((jc / 7) < 4 ? 1 : 2) : 0;
                    int clk = (ww_ == 7) ? ((jc % 7) < 4 ? 1 : 2) : 0;
                    if (rlk != rlq || clk != clq) v -= 100.0f;
                }
                acc[qt][jt][r] = v;
            }
        }
        float m = -1e30f;
#pragma unroll
        for (int jt = 0; jt < 4; ++jt)
#pragma unroll
            for (int r = 0; r < 4; ++r) m = fmaxf(m, acc[qt][jt][r]);
        m = fmaxf(m, __shfl_xor(m, 16));
        m = fmaxf(m, __shfl_xor(m, 32));
        float s = 0.f;
#pragma unroll
        for (int jt = 0; jt < 4; ++jt)
#pragma unroll
            for (int r = 0; r < 4; ++r) {
                float p = __expf(acc[qt][jt][r] - m);
                acc[qt][jt][r] = p;
                s += p;
            }
        s += __shfl_xor(s, 16);
        s += __shfl_xor(s, 32);
        float inv = 1.0f / s;
        int prow = (qt * 16 + lr) * 72;
#pragma unroll
        for (int jt = 0; jt < 4; ++jt) {
            unsigned lo = (unsigned)(unsigned short)f2bf(acc[qt][jt][0] * inv) |
                          ((unsigned)(unsigned short)f2bf(acc[qt][jt][1] * inv) << 16);
            unsigned hi = (unsigned)(unsigned short)f2bf(acc[qt][jt][2] * inv) |
                          ((unsigned)(unsigned short)f2bf(acc[qt][jt][3] * inv) << 16);
            *(int2*)&Pl[prow + jt * 16 + lg * 4] = make_int2((int)lo, (int)hi);
        }
    }

    f32x4 oacc[2][4];
#pragma unroll
    for (int mi = 0; mi < 2; ++mi)
#pragma unroll
        for (int ni = 0; ni < 4; ++ni) oacc[mi][ni] = fz;
#pragma unroll
    for (int kc = 0; kc < 2; ++kc) {
        FragU va[2], pb[4];
#pragma unroll
        for (int mi = 0; mi < 2; ++mi)
            va[mi].i4 = *(const int4*)&Vt[(mi * 16 + lr) * 72 + kc * 32 + lg * 8];
#pragma unroll
        for (int ni = 0; ni < 4; ++ni)
            pb[ni].i4 = *(const int4*)&Pl[(ni * 16 + lr) * 72 + kc * 32 + lg * 8];
#pragma unroll
        for (int mi = 0; mi < 2; ++mi)
#pragma unroll
            for (int ni = 0; ni < 4; ++ni)
                oacc[mi][ni] = __builtin_amdgcn_mfma_f32_16x16x32_bf16(
                    va[mi].b8, pb[ni].b8, oacc[mi][ni], 0, 0, 0);
    }

#pragma unroll
    for (int ni = 0; ni < 4; ++ni) {
        int qrow = ni * 16 + lr;
        if (qrow < 49) {
            int tok = tokbase + (qrow / 7) * 56 + (qrow % 7);
#pragma unroll
            for (int mi = 0; mi < 2; ++mi) {
                unsigned lo = (unsigned)(unsigned short)f2bf(oacc[mi][ni][0]) |
                              ((unsigned)(unsigned short)f2bf(oacc[mi][ni][1]) << 16);
                unsigned hi = (unsigned)(unsigned short)f2bf(oacc[mi][ni][2]) |
                              ((unsigned)(unsigned short)f2bf(oacc[mi][ni][3]) << 16);
                *(int2*)&aout[(size_t)tok * 128 + h * 32 + mi * 16 + lg * 4] =
                    make_int2((int)lo, (int)hi);
            }
        }
    }
}

// ------------- PatchMerging gather + LN -> bf16 rows [25088][512] ----------
__global__ __launch_bounds__(256) void k_pmln(
    const float* __restrict__ x, const float* __restrict__ g,
    const float* __restrict__ bt, short* __restrict__ outb) {
    int m2 = blockIdx.x * 4 + (threadIdx.x >> 6);
    int l = threadIdx.x & 63;
    int b = m2 / 784, r = m2 % 784;
    int h2 = r / 28, w2 = r % 28;
    int q0 = l * 8;
    int i2 = q0 >> 8, j2 = (q0 >> 7) & 1, c = q0 & 127;
    const float* src = x + (size_t)((b * 56 + 2 * h2 + i2) * 56 + 2 * w2 + j2) * 128 + c;
    float4 f0 = *(const float4*)src;
    float4 f1 = *(const float4*)(src + 4);
    float v[8] = {f0.x, f0.y, f0.z, f0.w, f1.x, f1.y, f1.z, f1.w};
    float s1 = 0.f, s2 = 0.f;
#pragma unroll
    for (int e = 0; e < 8; ++e) { s1 += v[e]; s2 = fmaf(v[e], v[e], s2); }
#pragma unroll
    for (int off = 32; off >= 1; off >>= 1) {
        s1 += __shfl_xor(s1, off);
        s2 += __shfl_xor(s2, off);
    }
    float mean = s1 * (1.0f / 512.0f);
    float var = s2 * (1.0f / 512.0f) - mean * mean;
    float rstd = rsqrtf(var + 1e-5f);
    union { int4 i4; short s8[8]; } u;
#pragma unroll
    for (int e = 0; e < 8; ++e)
        u.s8[e] = f2bf((v[e] - mean) * rstd * g[q0 + e] + bt[q0 + e]);
    *(int4*)(outb + (size_t)m2 * 512 + q0) = u.i4;
}

// ---------------------------------------------------------------------------
extern "C" void kernel_launch(void* const* d_in, const int* in_sizes, int n_in,
                              void* d_out, int out_size, void* d_ws, size_t ws_size,
                              hipStream_t stream) {
    const float* x_in   = (const float*)d_in[0];
    const float* qkv_w  = (const float*)d_in[1];
    const float* q_bias = (const float*)d_in[2];
    const float* v_bias = (const float*)d_in[3];
    const float* lscale = (const float*)d_in[4];
    const float* cpb_w1 = (const float*)d_in[5];
    const float* cpb_b1 = (const float*)d_in[6];
    const float* cpb_w2 = (const float*)d_in[7];
    const float* proj_w = (const float*)d_in[8];
    const float* proj_b = (const float*)d_in[9];
    const float* n1g    = (const float*)d_in[10];
    const float* n1b    = (const float*)d_in[11];
    const float* mw1    = (const float*)d_in[12];
    const float* mb1    = (const float*)d_in[13];
    const float* mw2    = (const float*)d_in[14];
    const float* mb2    = (const float*)d_in[15];
    const float* n2g    = (const float*)d_in[16];
    const float* n2b    = (const float*)d_in[17];
    const float* pmg    = (const float*)d_in[18];
    const float* pmb    = (const float*)d_in[19];
    const float* pmw    = (const float*)d_in[20];
    float* out = (float*)d_out;

    // workspace (floats):
    //  xcur 12,845,056 | R1 38,535,168 | wtail 163,840 | out169 704 | rpb64 16,384
    //  R1 overlays: qkvb bf16 [0,19.27M) ; attnout bf16 [19.27M,25.69M) ;
    //  hid bf16 [0,25.69M) ; pmin bf16 [0,6.43M) ; xb bf16 [25.69M,32.11M)
    float* wsf     = (float*)d_ws;
    float* xcur    = wsf;
    float* R1      = wsf + (size_t)12845056;
    short* qkvb    = (short*)R1;
    short* attnout = (short*)(R1 + (size_t)19267584);   // kTok*128 bf16
    short* hid     = (short*)R1;
    short* pmin    = (short*)R1;                        // 25088*512 bf16
    short* xb      = (short*)(R1 + (size_t)25690112);   // kTok*128 bf16
    float* wtail   = R1 + (size_t)38535168;
    short* wqkvb   = (short*)wtail;          // 49,152 bf16
    short* wprojb  = wqkvb + 49152;          // 16,384
    short* wm1b    = wprojb + 16384;         // 65,536
    short* wm2b    = wm1b + 65536;           // 65,536
    short* wpmb    = wm2b + 65536;           // 131,072
    float* out169  = wtail + 163840;
    float* rpb64   = out169 + 704;

    k_cvtx<<<6272, 256, 0, stream>>>(x_in, xb);

    for (int i = 0; i < 2; ++i) {
        int shift = i ? 3 : 0;
        const float* xi = (i == 0) ? x_in : xcur;
        k_cpb<<<169, 256, 0, stream>>>(cpb_w1 + i * 1024, cpb_b1 + i * 512,
                                       cpb_w2 + i * 2048, out169);
        k_rpb<<<64, 256, 0, stream>>>(out169, rpb64);
        k_cvtw<<<24, 256, 0, stream>>>(qkv_w + i * 49152, wqkvb, 16, 384);
        k_cvtw<<<8, 256, 0, stream>>>(proj_w + i * 16384, wprojb, 16, 128);
        k_cvtw<<<32, 256, 0, stream>>>(mw1 + i * 65536, wm1b, 16, 512);
        k_cvtw<<<32, 256, 0, stream>>>(mw2 + i * 65536, wm2b, 64, 128);

        k_gemm<128, 1, 6><<<4704, 256, 0, stream>>>(
            xb, wqkvb, q_bias + i * 128, v_bias + i * 128, qkvb, 384, shift);
        k_attn<<<2048, 256, 0, stream>>>(
            qkvb, rpb64, lscale + i * 4, attnout, shift);
        k_gemm_ln<128><<<784, 256, 0, stream>>>(
            attnout, wprojb, proj_b + i * 128, n1g + i * 128, n1b + i * 128,
            xi, xcur, xb, shift);
        k_gemm<128, 2, 8><<<6272, 256, 0, stream>>>(
            xb, wm1b, mb1 + i * 512, nullptr, hid, 512, 0);
        k_gemm_ln<512><<<784, 256, 0, stream>>>(
            hid, wm2b, mb2 + i * 128, n2g + i * 128, n2b + i * 128,
            xcur, xcur, xb, 0);
    }
    k_cvtw<<<64, 256, 0, stream>>>(pmw, wpmb, 64, 256);
    k_pmln<<<6272, 256, 0, stream>>>(xcur, pmg, pmb, pmin);
    k_gemm<512, 0, 4><<<784, 256, 0, stream>>>(
        pmin, wpmb, nullptr, nullptr, out, 256, 0);
}

// Round 6
// 488.606 us; speedup vs baseline: 3.3600x; 1.2722x over previous
//
#include <hip/hip_runtime.h>
#include <math.h>

// ---------------------------------------------------------------------------
// SwinV2 stage: B=32, H=W=56, C=128, NH=4, hd=32, WS=7, N=49, DEPTH=2, shift=3
// Round 6: weights staged in LDS (kills per-MFMA L2-latency dependency);
// W image pre-swizzled for conflict-free ds_read_b128; k_gemm_ln BM=64.
// ---------------------------------------------------------------------------

namespace {
constexpr int kTok = 32 * 56 * 56;   // 100352 tokens
}

typedef __attribute__((ext_vector_type(8))) short bf16x8;
typedef __attribute__((ext_vector_type(4))) float f32x4;

union FragU {
    int4 i4;
    bf16x8 b8;
    unsigned short u[8];
};

__device__ __forceinline__ short f2bf(float f) {
    unsigned u = __float_as_uint(f);
    return (short)((u + 0x7FFFu + ((u >> 16) & 1u)) >> 16);
}
__device__ __forceinline__ float bf2f(unsigned short u) {
    return __uint_as_float(((unsigned)u) << 16);
}
__device__ __forceinline__ float gelu_f(float x) {
    return 0.5f * x * (1.0f + erff(x * 0.70710678118654752f));
}

// --------------------------- CPB MLP (tiny) --------------------------------
__global__ __launch_bounds__(256) void k_cpb(
    const float* __restrict__ w1, const float* __restrict__ b1,
    const float* __restrict__ w2, float* __restrict__ out169) {
    int t = blockIdx.x;  // 0..168
    int ia = t / 13, ib = t % 13;
    float r0 = (float)(ia - 6) * (8.0f / 6.0f);
    float s0 = (r0 > 0.f) ? 1.f : (r0 < 0.f ? -1.f : 0.f);
    float t0 = s0 * log2f(fabsf(r0) + 1.0f) * (1.0f / 3.0f);
    float r1 = (float)(ib - 6) * (8.0f / 6.0f);
    float s1 = (r1 > 0.f) ? 1.f : (r1 < 0.f ? -1.f : 0.f);
    float t1 = s1 * log2f(fabsf(r1) + 1.0f) * (1.0f / 3.0f);

    int tid = threadIdx.x;
    float p0 = 0, p1 = 0, p2 = 0, p3 = 0;
    for (int c = tid; c < 512; c += 256) {
        float hv = fmaxf(t0 * w1[c] + t1 * w1[512 + c] + b1[c], 0.0f);
        p0 += hv * w2[c * 4 + 0];
        p1 += hv * w2[c * 4 + 1];
        p2 += hv * w2[c * 4 + 2];
        p3 += hv * w2[c * 4 + 3];
    }
    __shared__ float red[256][4];
    red[tid][0] = p0; red[tid][1] = p1; red[tid][2] = p2; red[tid][3] = p3;
    __syncthreads();
    for (int s = 128; s > 0; s >>= 1) {
        if (tid < s) {
            red[tid][0] += red[tid + s][0];
            red[tid][1] += red[tid + s][1];
            red[tid][2] += red[tid + s][2];
            red[tid][3] += red[tid + s][3];
        }
        __syncthreads();
    }
    if (tid < 4) out169[t * 4 + tid] = red[0][tid];
}

// rpb64[h][qrow64][krow64]; krow>=49 -> -30000 (k-pad baked in)
__global__ void k_rpb(const float* __restrict__ out169, float* __restrict__ rpb64) {
    int e = blockIdx.x * 256 + threadIdx.x;
    if (e >= 4 * 64 * 64) return;
    int h = e >> 12, r = e & 4095;
    int i = r >> 6, j = r & 63;
    float val;
    if (j >= 49) {
        val = -30000.0f;
    } else if (i >= 49) {
        val = 0.0f;
    } else {
        int dp = i / 7 - j / 7 + 6;
        int dq = i % 7 - j % 7 + 6;
        float v = out169[(dp * 13 + dq) * 4 + h];
        val = 16.0f / (1.0f + expf(-v));
    }
    rpb64[e] = val;
}

// ------------------- weight fp32 -> bf16 tiled image -----------------------
// Logical slot (nt*Kb + kb)*64 + nn holds W[kb*8+e][nt*64+nn], e=0..7.
// Stored at physical nn' = (nn & ~3) | ((nn ^ kb) & 3): bank-spread fragment
// reads from LDS while the global->LDS chunk copy stays linear.
__global__ __launch_bounds__(256) void k_cvtw(
    const float* __restrict__ W, short* __restrict__ Wb, int Kb, int N) {
    int slt = blockIdx.x * 256 + threadIdx.x;
    if (slt >= Kb * N) return;
    int nn = slt & 63;
    int tmp = slt >> 6;
    int kb = tmp % Kb;
    int nt = tmp / Kb;
    int n = nt * 64 + nn;
    int k0 = kb * 8;
    union { int4 i4; short s8[8]; } u;
#pragma unroll
    for (int e = 0; e < 8; ++e) u.s8[e] = f2bf(W[(size_t)(k0 + e) * N + n]);
    int nns = (nn & ~3) | ((nn ^ kb) & 3);
    *(int4*)(Wb + (((size_t)tmp) * 64 + nns) * 8) = u.i4;
}

// ------------------- activation fp32 -> bf16 rows --------------------------
__global__ __launch_bounds__(256) void k_cvtx(
    const float* __restrict__ x, short* __restrict__ xb) {
    size_t e = ((size_t)blockIdx.x * 256 + threadIdx.x) * 8;
    const float* src = x + e;
    float4 f0 = *(const float4*)src;
    float4 f1 = *(const float4*)(src + 4);
    union { int4 i4; short s8[8]; } u;
    u.s8[0] = f2bf(f0.x); u.s8[1] = f2bf(f0.y);
    u.s8[2] = f2bf(f0.z); u.s8[3] = f2bf(f0.w);
    u.s8[4] = f2bf(f1.x); u.s8[5] = f2bf(f1.y);
    u.s8[6] = f2bf(f1.z); u.s8[7] = f2bf(f1.w);
    *(int4*)(xb + e) = u.i4;
}

// --------------------------- MFMA GEMM (bf16 A) ----------------------------
// C[M x N] = A[M x K] @ W[K x N] (+epilogue). BM=128, BN=64, 4 waves.
// A and W chunk both staged in LDS. 1D grid, XCD-chunked.
// EPI: 0 = raw fp32; 1 = qkv bias -> bf16 out (stride 384), roll on A;
//      2 = bias + gelu -> bf16 out (stride 512).
template <int K, int EPI, int NT>
__global__ __launch_bounds__(256) void k_gemm(
    const short* __restrict__ Ain, const short* __restrict__ Wb,
    const float* __restrict__ bias0, const float* __restrict__ bias1,
    void* __restrict__ Out, int ostride, int shift) {
    constexpr int Kb = K / 8;
    constexpr int NC = K / 128;
    __shared__ int4 As4[2048];  // [16 kb][128 m], XOR-swizzled (8-wide)
    __shared__ int4 Ws4[1024];  // [16 kb][64 nn], XOR-swizzled (4-wide, in image)
    int tid = threadIdx.x;
    int nwg = gridDim.x;
    int chunk = nwg >> 3;
    int lid = (blockIdx.x & 7) * chunk + (blockIdx.x >> 3);
    int mt = lid / NT, nt = lid - mt * NT;
    int mb = mt * 128;
    int w = tid >> 6, l = tid & 63, lr = l & 15, lg = l >> 4;
    const f32x4 fz = {0.f, 0.f, 0.f, 0.f};
    f32x4 acc[2][4];
#pragma unroll
    for (int mi = 0; mi < 2; ++mi)
#pragma unroll
        for (int ni = 0; ni < 4; ++ni) acc[mi][ni] = fz;

    for (int c = 0; c < NC; ++c) {
        if (c) __syncthreads();
#pragma unroll
        for (int it = 0; it < 8; ++it) {
            int s = it * 256 + tid;
            int m = s >> 4, kb = s & 15;
            int gm = mb + m;
            if (EPI == 1 && shift) {
                int b = gm / 3136, r = gm % 3136;
                int hh = r / 56 + shift; if (hh >= 56) hh -= 56;
                int ww = r % 56 + shift; if (ww >= 56) ww -= 56;
                gm = b * 3136 + hh * 56 + ww;
            }
            int slot = kb * 128 + ((m & ~7) | ((m ^ kb) & 7));
            As4[slot] = *(const int4*)(Ain + (size_t)gm * K + c * 128 + kb * 8);
        }
        {
            const int4* wsrc = (const int4*)(Wb + ((size_t)nt * Kb + c * 16) * 64 * 8);
#pragma unroll
            for (int it = 0; it < 4; ++it) Ws4[it * 256 + tid] = wsrc[it * 256 + tid];
        }
        __syncthreads();
#pragma unroll
        for (int kk = 0; kk < 4; ++kk) {
            int kbl = kk * 4 + lg;
            int m0 = w * 32 + lr;
            bf16x8 a0 = *(const bf16x8*)&As4[kbl * 128 + ((m0 & ~7) | ((m0 ^ kbl) & 7))];
            int m1 = m0 + 16;
            bf16x8 a1 = *(const bf16x8*)&As4[kbl * 128 + ((m1 & ~7) | ((m1 ^ kbl) & 7))];
#pragma unroll
            for (int ni = 0; ni < 4; ++ni) {
                int nn = lr + 16 * ni;
                bf16x8 bfr = *(const bf16x8*)&Ws4[kbl * 64 + ((nn & ~3) | ((nn ^ kbl) & 3))];
                acc[0][ni] = __builtin_amdgcn_mfma_f32_16x16x32_bf16(a0, bfr, acc[0][ni], 0, 0, 0);
                acc[1][ni] = __builtin_amdgcn_mfma_f32_16x16x32_bf16(a1, bfr, acc[1][ni], 0, 0, 0);
            }
        }
    }
#pragma unroll
    for (int ni = 0; ni < 4; ++ni) {
        int col = nt * 64 + ni * 16 + lr;
        float bv = 0.f;
        if (EPI == 1) bv = (col < 128) ? bias0[col] : ((col < 256) ? 0.f : bias1[col - 256]);
        if (EPI == 2) bv = bias0[col];
#pragma unroll
        for (int mi = 0; mi < 2; ++mi) {
#pragma unroll
            for (int r = 0; r < 4; ++r) {
                int row = mb + w * 32 + mi * 16 + lg * 4 + r;
                float v = acc[mi][ni][r] + bv;
                if (EPI == 0) {
                    ((float*)Out)[(size_t)row * ostride + col] = v;
                } else if (EPI == 1) {
                    ((short*)Out)[(size_t)row * 384 + col] = f2bf(v);
                } else {
                    ((short*)Out)[(size_t)row * 512 + col] = f2bf(gelu_f(v));
                }
            }
        }
    }
}

// ------------- MFMA GEMM + bias + LN + residual (+roll-back) ---------------
// N=128 full row. BM=64, 4 waves x 16 rows (acc[8]). W (both halves) in LDS.
// xout[mo] = resid[mo] + LN(A[row] @ W + bias); also writes bf16 copy xoutb.
template <int K>
__global__ __launch_bounds__(256) void k_gemm_ln(
    const short* __restrict__ Ain, const short* __restrict__ Wb,
    const float* __restrict__ bias, const float* __restrict__ g,
    const float* __restrict__ bt, const float* __restrict__ resid,
    float* __restrict__ xout, short* __restrict__ xoutb, int shift) {
    constexpr int Kb = K / 8;
    constexpr int NC = K / 128;
    __shared__ int4 As4[1024];  // [16 kb][64 m]
    __shared__ int4 Ws4[2048];  // [2 ntw][16 kb][64 nn]
    int tid = threadIdx.x;
    int mb = blockIdx.x * 64;
    int w = tid >> 6, l = tid & 63, lr = l & 15, lg = l >> 4;
    const f32x4 fz = {0.f, 0.f, 0.f, 0.f};
    f32x4 acc[8];
#pragma unroll
    for (int ni = 0; ni < 8; ++ni) acc[ni] = fz;

    for (int c = 0; c < NC; ++c) {
        if (c) __syncthreads();
#pragma unroll
        for (int it = 0; it < 4; ++it) {
            int s = it * 256 + tid;
            int m = s >> 4, kb = s & 15;
            int slot = kb * 64 + ((m & ~7) | ((m ^ kb) & 7));
            As4[slot] = *(const int4*)(Ain + (size_t)(mb + m) * K + c * 128 + kb * 8);
        }
        {
            const int4* w0 = (const int4*)(Wb + ((size_t)(c * 16)) * 64 * 8);
            const int4* w1 = (const int4*)(Wb + ((size_t)(Kb + c * 16)) * 64 * 8);
#pragma unroll
            for (int it = 0; it < 4; ++it) {
                Ws4[it * 256 + tid] = w0[it * 256 + tid];
                Ws4[1024 + it * 256 + tid] = w1[it * 256 + tid];
            }
        }
        __syncthreads();
#pragma unroll
        for (int kk = 0; kk < 4; ++kk) {
            int kbl = kk * 4 + lg;
            int m0 = w * 16 + lr;
            bf16x8 a0 = *(const bf16x8*)&As4[kbl * 64 + ((m0 & ~7) | ((m0 ^ kbl) & 7))];
#pragma unroll
            for (int ni = 0; ni < 8; ++ni) {
                int nn = lr + 16 * (ni & 3);
                bf16x8 bfr = *(const bf16x8*)&Ws4[(ni >> 2) * 1024 + kbl * 64 +
                                                  ((nn & ~3) | ((nn ^ kbl) & 3))];
                acc[ni] = __builtin_amdgcn_mfma_f32_16x16x32_bf16(a0, bfr, acc[ni], 0, 0, 0);
            }
        }
    }
    float bv[8], gv[8], btv[8];
#pragma unroll
    for (int ni = 0; ni < 8; ++ni) {
        int col = ni * 16 + lr;
        bv[ni] = bias[col]; gv[ni] = g[col]; btv[ni] = bt[col];
    }
#pragma unroll
    for (int r = 0; r < 4; ++r) {
        int row = mb + w * 16 + lg * 4 + r;
        float v[8];
        float s1 = 0.f, s2 = 0.f;
#pragma unroll
        for (int ni = 0; ni < 8; ++ni) {
            v[ni] = acc[ni][r] + bv[ni];
            s1 += v[ni];
            s2 = fmaf(v[ni], v[ni], s2);
        }
#pragma unroll
        for (int off = 8; off >= 1; off >>= 1) {
            s1 += __shfl_xor(s1, off);
            s2 += __shfl_xor(s2, off);
        }
        float mean = s1 * (1.0f / 128.0f);
        float var = s2 * (1.0f / 128.0f) - mean * mean;
        float rstd = rsqrtf(var + 1e-5f);
        int mo = row;
        if (shift) {
            int b = row / 3136, rr = row % 3136;
            int hh = rr / 56 + shift; if (hh >= 56) hh -= 56;
            int ww = rr % 56 + shift; if (ww >= 56) ww -= 56;
            mo = b * 3136 + hh * 56 + ww;
        }
        size_t base = (size_t)mo * 128;
#pragma unroll
        for (int ni = 0; ni < 8; ++ni) {
            int col = ni * 16 + lr;
            float o = resid[base + col] + (v[ni] - mean) * rstd * gv[ni] + btv[ni];
            xout[base + col] = o;
            xoutb[base + col] = f2bf(o);
        }
    }
}

// --------------------------- MFMA windowed attention -----------------------
__global__ __launch_bounds__(256) void k_attn(
    const short* __restrict__ qkv, const float* __restrict__ rpb64,
    const float* __restrict__ ls, short* __restrict__ aout, int shift) {
    __shared__ short lds[4 * 6912];
    int wid = blockIdx.x;
    int b = wid >> 6, wrem = wid & 63;
    int wh = wrem >> 3, ww_ = wrem & 7;
    int h = threadIdx.x >> 6;
    int l = threadIdx.x & 63, lr = l & 15, lg = l >> 4;
    short* Pl = lds + h * 6912;
    short* Vt = Pl + 4608;
    int tokbase = b * 3136 + wh * 7 * 56 + ww_ * 7;

    float scale = __expf(fminf(ls[h], 4.6051702f));  // ln(100)
    int4 qf[4], kf[4];
    const int4 zero4 = make_int4(0, 0, 0, 0);
#pragma unroll
    for (int t = 0; t < 4; ++t) {
        int i = t * 16 + lr;
        bool valid = (i < 49);
        int tok = tokbase + (i / 7) * 56 + (i % 7);
        const short* base = qkv + (size_t)tok * 384 + h * 32 + lg * 8;
        qf[t] = valid ? *(const int4*)base : zero4;
        kf[t] = valid ? *(const int4*)(base + 128) : zero4;
    }
#pragma unroll
    for (int t = 0; t < 4; ++t) {
#pragma unroll
        for (int m = 0; m < 2; ++m) {
            FragU u; u.i4 = m ? kf[t] : qf[t];
            float x[8], ss = 0.f;
#pragma unroll
            for (int e = 0; e < 8; ++e) { x[e] = bf2f(u.u[e]); ss = fmaf(x[e], x[e], ss); }
            ss += __shfl_xor(ss, 16);
            ss += __shfl_xor(ss, 32);
            float inv = 1.0f / fmaxf(sqrtf(ss), 1e-12f);
            if (m == 0) inv *= scale;
#pragma unroll
            for (int e = 0; e < 8; ++e) u.u[e] = (unsigned short)f2bf(x[e] * inv);
            if (m) kf[t] = u.i4; else qf[t] = u.i4;
        }
    }

    for (int t = l; t < 480; t += 64) {
        Vt[(t / 15) * 72 + 49 + (t % 15)] = 0;
    }
    for (int t = l; t < 196; t += 64) {
        int j = t >> 2, dq = t & 3;
        int tok = tokbase + (j / 7) * 56 + (j % 7);
        FragU u;
        u.i4 = *(const int4*)(qkv + (size_t)tok * 384 + 256 + h * 32 + dq * 8);
#pragma unroll
        for (int e = 0; e < 8; ++e) Vt[(dq * 8 + e) * 72 + j] = (short)u.u[e];
    }

    const f32x4 fz = {0.f, 0.f, 0.f, 0.f};
    f32x4 acc[4][4];
#pragma unroll
    for (int qt = 0; qt < 4; ++qt)
#pragma unroll
        for (int jt = 0; jt < 4; ++jt) acc[qt][jt] = fz;
#pragma unroll
    for (int jt = 0; jt < 4; ++jt) {
        FragU a; a.i4 = kf[jt];
#pragma unroll
        for (int qt = 0; qt < 4; ++qt) {
            FragU bq; bq.i4 = qf[qt];
            acc[qt][jt] = __builtin_amdgcn_mfma_f32_16x16x32_bf16(a.b8, bq.b8, acc[qt][jt], 0, 0, 0);
        }
    }

    bool edge = (shift != 0) && ((wh == 7) || (ww_ == 7));
    const float* rbase = rpb64 + h * 4096;
#pragma unroll
    for (int qt = 0; qt < 4; ++qt) {
        int qi = qt * 16 + lr;
        int qc = (qi < 49) ? qi : 48;
        int rlq = 0, clq = 0;
        if (edge) {
            rlq = (wh == 7) ? ((qc / 7) < 4 ? 1 : 2) : 0;
            clq = (ww_ == 7) ? ((qc % 7) < 4 ? 1 : 2) : 0;
        }
#pragma unroll
        for (int jt = 0; jt < 4; ++jt) {
            float4 rv = *(const float4*)(rbase + qc * 64 + jt * 16 + lg * 4);
            float rr[4] = {rv.x, rv.y, rv.z, rv.w};
#pragma unroll
            for (int r = 0; r < 4; ++r) {
                float v = acc[qt][jt][r] + rr[r];
                if (edge) {
                    int j = jt * 16 + lg * 4 + r;
                    int jc = (j < 49) ? j : 48;
                    int rlk = (wh == 7) ? ((jc / 7) < 4 ? 1 : 2) : 0;
                    int clk = (ww_ == 7) ? ((jc % 7) < 4 ? 1 : 2) : 0;
                    if (rlk != rlq || clk != clq) v -= 100.0f;
                }
                acc[qt][jt][r] = v;
            }
        }
        float m = -1e30f;
#pragma unroll
        for (int jt = 0; jt < 4; ++jt)
#pragma unroll
            for (int r = 0; r < 4; ++r) m = fmaxf(m, acc[qt][jt][r]);
        m = fmaxf(m, __shfl_xor(m, 16));
        m = fmaxf(m, __shfl_xor(m, 32));
        float s = 0.f;
#pragma unroll
        for (int jt = 0; jt < 4; ++jt)
#pragma unroll
            for (int r = 0; r < 4; ++r) {
                float p = __expf(acc[qt][jt][r] - m);
                acc[qt][jt][r] = p;
                s += p;
            }
        s += __shfl_xor(s, 16);
        s += __shfl_xor(s, 32);
        float inv = 1.0f / s;
        int prow = (qt * 16 + lr) * 72;
#pragma unroll
        for (int jt = 0; jt < 4; ++jt) {
            unsigned lo = (unsigned)(unsigned short)f2bf(acc[qt][jt][0] * inv) |
                          ((unsigned)(unsigned short)f2bf(acc[qt][jt][1] * inv) << 16);
            unsigned hi = (unsigned)(unsigned short)f2bf(acc[qt][jt][2] * inv) |
                          ((unsigned)(unsigned short)f2bf(acc[qt][jt][3] * inv) << 16);
            *(int2*)&Pl[prow + jt * 16 + lg * 4] = make_int2((int)lo, (int)hi);
        }
    }

    f32x4 oacc[2][4];
#pragma unroll
    for (int mi = 0; mi < 2; ++mi)
#pragma unroll
        for (int ni = 0; ni < 4; ++ni) oacc[mi][ni] = fz;
#pragma unroll
    for (int kc = 0; kc < 2; ++kc) {
        FragU va[2], pb[4];
#pragma unroll
        for (int mi = 0; mi < 2; ++mi)
            va[mi].i4 = *(const int4*)&Vt[(mi * 16 + lr) * 72 + kc * 32 + lg * 8];
#pragma unroll
        for (int ni = 0; ni < 4; ++ni)
            pb[ni].i4 = *(const int4*)&Pl[(ni * 16 + lr) * 72 + kc * 32 + lg * 8];
#pragma unroll
        for (int mi = 0; mi < 2; ++mi)
#pragma unroll
            for (int ni = 0; ni < 4; ++ni)
                oacc[mi][ni] = __builtin_amdgcn_mfma_f32_16x16x32_bf16(
                    va[mi].b8, pb[ni].b8, oacc[mi][ni], 0, 0, 0);
    }

#pragma unroll
    for (int ni = 0; ni < 4; ++ni) {
        int qrow = ni * 16 + lr;
        if (qrow < 49) {
            int tok = tokbase + (qrow / 7) * 56 + (qrow % 7);
#pragma unroll
            for (int mi = 0; mi < 2; ++mi) {
                unsigned lo = (unsigned)(unsigned short)f2bf(oacc[mi][ni][0]) |
                              ((unsigned)(unsigned short)f2bf(oacc[mi][ni][1]) << 16);
                unsigned hi = (unsigned)(unsigned short)f2bf(oacc[mi][ni][2]) |
                              ((unsigned)(unsigned short)f2bf(oacc[mi][ni][3]) << 16);
                *(int2*)&aout[(size_t)tok * 128 + h * 32 + mi * 16 + lg * 4] =
                    make_int2((int)lo, (int)hi);
            }
        }
    }
}

// ------------- PatchMerging gather + LN -> bf16 rows [25088][512] ----------
__global__ __launch_bounds__(256) void k_pmln(
    const float* __restrict__ x, const float* __restrict__ g,
    const float* __restrict__ bt, short* __restrict__ outb) {
    int m2 = blockIdx.x * 4 + (threadIdx.x >> 6);
    int l = threadIdx.x & 63;
    int b = m2 / 784, r = m2 % 784;
    int h2 = r / 28, w2 = r % 28;
    int q0 = l * 8;
    int i2 = q0 >> 8, j2 = (q0 >> 7) & 1, c = q0 & 127;
    const float* src = x + (size_t)((b * 56 + 2 * h2 + i2) * 56 + 2 * w2 + j2) * 128 + c;
    float4 f0 = *(const float4*)src;
    float4 f1 = *(const float4*)(src + 4);
    float v[8] = {f0.x, f0.y, f0.z, f0.w, f1.x, f1.y, f1.z, f1.w};
    float s1 = 0.f, s2 = 0.f;
#pragma unroll
    for (int e = 0; e < 8; ++e) { s1 += v[e]; s2 = fmaf(v[e], v[e], s2); }
#pragma unroll
    for (int off = 32; off >= 1; off >>= 1) {
        s1 += __shfl_xor(s1, off);
        s2 += __shfl_xor(s2, off);
    }
    float mean = s1 * (1.0f / 512.0f);
    float var = s2 * (1.0f / 512.0f) - mean * mean;
    float rstd = rsqrtf(var + 1e-5f);
    union { int4 i4; short s8[8]; } u;
#pragma unroll
    for (int e = 0; e < 8; ++e)
        u.s8[e] = f2bf((v[e] - mean) * rstd * g[q0 + e] + bt[q0 + e]);
    *(int4*)(outb + (size_t)m2 * 512 + q0) = u.i4;
}

// ---------------------------------------------------------------------------
extern "C" void kernel_launch(void* const* d_in, const int* in_sizes, int n_in,
                              void* d_out, int out_size, void* d_ws, size_t ws_size,
                              hipStream_t stream) {
    const float* x_in   = (const float*)d_in[0];
    const float* qkv_w  = (const float*)d_in[1];
    const float* q_bias = (const float*)d_in[2];
    const float* v_bias = (const float*)d_in[3];
    const float* lscale = (const float*)d_in[4];
    const float* cpb_w1 = (const float*)d_in[5];
    const float* cpb_b1 = (const float*)d_in[6];
    const float* cpb_w2 = (const float*)d_in[7];
    const float* proj_w = (const float*)d_in[8];
    const float* proj_b = (const float*)d_in[9];
    const float* n1g    = (const float*)d_in[10];
    const float* n1b    = (const float*)d_in[11];
    const float* mw1    = (const float*)d_in[12];
    const float* mb1    = (const float*)d_in[13];
    const float* mw2    = (const float*)d_in[14];
    const float* mb2    = (const float*)d_in[15];
    const float* n2g    = (const float*)d_in[16];
    const float* n2b    = (const float*)d_in[17];
    const float* pmg    = (const float*)d_in[18];
    const float* pmb    = (const float*)d_in[19];
    const float* pmw    = (const float*)d_in[20];
    float* out = (float*)d_out;

    // workspace (floats):
    //  xcur 12,845,056 | R1 38,535,168 | wtail 163,840 | out169 704 | rpb64 16,384
    //  R1 overlays: qkvb bf16 [0,19.27M) ; attnout bf16 [19.27M,25.69M) ;
    //  hid bf16 [0,25.69M) ; pmin bf16 [0,6.43M) ; xb bf16 [25.69M,32.11M)
    float* wsf     = (float*)d_ws;
    float* xcur    = wsf;
    float* R1      = wsf + (size_t)12845056;
    short* qkvb    = (short*)R1;
    short* attnout = (short*)(R1 + (size_t)19267584);   // kTok*128 bf16
    short* hid     = (short*)R1;
    short* pmin    = (short*)R1;                        // 25088*512 bf16
    short* xb      = (short*)(R1 + (size_t)25690112);   // kTok*128 bf16
    float* wtail   = R1 + (size_t)38535168;
    short* wqkvb   = (short*)wtail;          // 49,152 bf16
    short* wprojb  = wqkvb + 49152;          // 16,384
    short* wm1b    = wprojb + 16384;         // 65,536
    short* wm2b    = wm1b + 65536;           // 65,536
    short* wpmb    = wm2b + 65536;           // 131,072
    float* out169  = wtail + 163840;
    float* rpb64   = out169 + 704;

    k_cvtx<<<6272, 256, 0, stream>>>(x_in, xb);

    for (int i = 0; i < 2; ++i) {
        int shift = i ? 3 : 0;
        const float* xi = (i == 0) ? x_in : xcur;
        k_cpb<<<169, 256, 0, stream>>>(cpb_w1 + i * 1024, cpb_b1 + i * 512,
                                       cpb_w2 + i * 2048, out169);
        k_rpb<<<64, 256, 0, stream>>>(out169, rpb64);
        k_cvtw<<<24, 256, 0, stream>>>(qkv_w + i * 49152, wqkvb, 16, 384);
        k_cvtw<<<8, 256, 0, stream>>>(proj_w + i * 16384, wprojb, 16, 128);
        k_cvtw<<<32, 256, 0, stream>>>(mw1 + i * 65536, wm1b, 16, 512);
        k_cvtw<<<32, 256, 0, stream>>>(mw2 + i * 65536, wm2b, 64, 128);

        k_gemm<128, 1, 6><<<4704, 256, 0, stream>>>(
            xb, wqkvb, q_bias + i * 128, v_bias + i * 128, qkvb, 384, shift);
        k_attn<<<2048, 256, 0, stream>>>(
            qkvb, rpb64, lscale + i * 4, attnout, shift);
        k_gemm_ln<128><<<1568, 256, 0, stream>>>(
            attnout, wprojb, proj_b + i * 128, n1g + i * 128, n1b + i * 128,
            xi, xcur, xb, shift);
        k_gemm<128, 2, 8><<<6272, 256, 0, stream>>>(
            xb, wm1b, mb1 + i * 512, nullptr, hid, 512, 0);
        k_gemm_ln<512><<<1568, 256, 0, stream>>>(
            hid, wm2b, mb2 + i * 128, n2g + i * 128, n2b + i * 128,
            xcur, xcur, xb, 0);
    }
    k_cvtw<<<64, 256, 0, stream>>>(pmw, wpmb, 64, 256);
    k_pmln<<<6272, 256, 0, stream>>>(xcur, pmg, pmb, pmin);
    k_gemm<512, 0, 4><<<784, 256, 0, stream>>>(
        pmin, wpmb, nullptr, nullptr, out, 256, 0);
}